// Round 11
// baseline (329.578 us; speedup 1.0000x reference)
//
#include <hip/hip_runtime.h>
#include <hip/hip_bf16.h>

#define BD 4096
#define ID 1024
#define FD 2048

typedef __bf16 v8bf __attribute__((ext_vector_type(8)));
typedef float  v4f  __attribute__((ext_vector_type(4)));

struct alignas(8) bf4 { __hip_bfloat16 x, y, z, w; };

__device__ inline __hip_bfloat16 bf(float f) { return __float2bfloat16(f); }
__device__ inline float sig(float x) { return 1.f / (1.f + expf(-x)); }

__device__ inline void gload16(const __hip_bfloat16* g, __hip_bfloat16* l) {
  __builtin_amdgcn_global_load_lds(
      (const __attribute__((address_space(1))) void*)g,
      (__attribute__((address_space(3))) void*)l, 16, 0, 0);
}

// ---------- quantum state prep (+ zero accumulators incl. ticket counter) ----
__global__ void k_prep_q(const float* ar, const float* ai, const float* ph,
                         const int* tstep, float* qs, float* pamp,
                         float* scal, float* tau_raw, float* dec_raw) {
  int j = blockIdx.x * 256 + threadIdx.x;
  if (j < 4) scal[j] = 0.f;                 // scal[3] doubles as int ticket = 0
  if (j < FD) { tau_raw[j] = 0.f; dec_raw[j] = 0.f; }
  if (j >= FD) return;
  float t = (float)tstep[0];
  float4 a = ((const float4*)ar)[j];
  float4 b = ((const float4*)ai)[j];
  float4 p = ((const float4*)ph)[j];
  float sr = 0.f, si = 0.f, pm = 0.f;
  {
    float c, s, rc, ic;
    c = cosf(p.x + 0.1f * t); s = sinf(p.x + 0.1f * t);
    rc = a.x * c; ic = b.x * s; sr += rc; si += ic; pm += rc * rc + ic * ic;
    c = cosf(p.y + 0.1f * t); s = sinf(p.y + 0.1f * t);
    rc = a.y * c; ic = b.y * s; sr += rc; si += ic; pm += rc * rc + ic * ic;
    c = cosf(p.z + 0.1f * t); s = sinf(p.z + 0.1f * t);
    rc = a.z * c; ic = b.z * s; sr += rc; si += ic; pm += rc * rc + ic * ic;
    c = cosf(p.w + 0.1f * t); s = sinf(p.w + 0.1f * t);
    rc = a.w * c; ic = b.w * s; sr += rc; si += ic; pm += rc * rc + ic * ic;
  }
  qs[j] = sr * expf(-si * si);
  pamp[j] = 0.25f * pm;
}

// ---------- f32 -> bf16 cast: inputs then hidden in one launch ----------
__global__ void k_cast(const float* s1, __hip_bfloat16* d1, int n1,
                       const float* s2, __hip_bfloat16* d2) {
  int i = blockIdx.x * blockDim.x + threadIdx.x;
  const float* src = s1; __hip_bfloat16* dst = d1;
  if (i >= n1) { i -= n1; src = s2; dst = d2; }
  float4 v = ((const float4*)src)[i];
  bf4 o{bf(v.x), bf(v.y), bf(v.z), bf(v.w)};
  ((bf4*)dst)[i] = o;
}

// ---------- transpose + cast (+ optional M = P + E*corr[col]) ----------
__global__ void k_tcast(const float* src, const float* src2, const float* corr,
                        __hip_bfloat16* dst, int R, int C, int useM) {
  __shared__ float t[32][33];
  int tx = threadIdx.x, ty = threadIdx.y;   // block (32,8)
  int x = blockIdx.x * 32 + tx;             // src col
  int yb = blockIdx.y * 32;                 // src row base
  float cr = useM ? corr[x] : 0.f;
#pragma unroll
  for (int j = 0; j < 4; j++) {
    int y = yb + ty + j * 8;
    float v = src[(size_t)y * C + x];
    if (useM) v += src2[(size_t)y * C + x] * cr;
    t[ty + j * 8][tx] = v;
  }
  __syncthreads();
#pragma unroll
  for (int j = 0; j < 4; j++) {
    int orow = blockIdx.x * 32 + ty + j * 8;  // = src col
    int ocol = yb + tx;                       // = src row
    dst[(size_t)orow * R + ocol] = bf(t[tx][ty + j * 8]);
  }
}

// ---------- split-K matvec: raw[j] += sum_i qs[i] * W[i][j] ----------
__global__ void k_matvec(const float* qs, const float* Wt, const float* Wd,
                         float* tau_raw, float* dec_raw) {
  int j = blockIdx.x * 256 + threadIdx.x;     // grid.x = 8
  int i0 = blockIdx.y * 128;                  // grid.y = 16
  const float* W = blockIdx.z ? Wd : Wt;      // grid.z = 2
  float* out = blockIdx.z ? dec_raw : tau_raw;
  __shared__ float q[128];
  if (threadIdx.x < 128) q[threadIdx.x] = qs[i0 + threadIdx.x];
  __syncthreads();
  float acc = 0.f;
#pragma unroll 8
  for (int i = 0; i < 128; i++) acc = fmaf(q[i], W[(size_t)(i0 + i) * FD + j], acc);
  atomicAdd(&out[j], acc);
}

// ---------- post: tau_q, s, deco, qact, scalar partials ----------
__global__ void k_post(const float* tau_raw, const float* dec_raw, const float* qs,
                       const float* b_tau, const float* b_dec, const int* tstep,
                       float* s_arr, float* qact, float* scal) {
  int j = blockIdx.x * 256 + threadIdx.x;
  float t = (float)tstep[0];
  float coh = expf(-0.01f * t);
  float tq = (5.f + 45.f * sig(tau_raw[j] + b_tau[j])) / 3.2f;
  s_arr[j] = 0.03125f / tq;                  // dt_q / tau_q, dt_q = 0.1/3.2
  float dec = sig(dec_raw[j] + b_dec[j]);
  qact[j] = qs[j] * dec * coh;
  float tsum = tq, dsum = dec;
  for (int off = 32; off; off >>= 1) {
    tsum += __shfl_down(tsum, off);
    dsum += __shfl_down(dsum, off);
  }
  __shared__ float rt[4], rd[4];
  int w = threadIdx.x >> 6;
  if ((threadIdx.x & 63) == 0) { rt[w] = tsum; rd[w] = dsum; }
  __syncthreads();
  if (threadIdx.x == 0) {
    atomicAdd(&scal[1], rd[0] + rd[1] + rd[2] + rd[3]);
    atomicAdd(&scal[2], rt[0] + rt[1] + rt[2] + rt[3]);
  }
}

// ---------- split-K GEMM: 3 uniform K=1024 parts -> bf16 partial buffers ----
// 128x128 tile, m97 dbuf 2-barrier skeleton + R6 swizzle (0 conflicts).
// grid (32,16,3): bz=0 ent k[0:1024] -> g0; bz=1 ent k[1024:2048] -> g1;
// bz=2 xproj k[0:1024] -> gx. 1536 blocks, 32 K-steps each, 4 resident/CU.
__global__ __launch_bounds__(256, 4) void k_gemm_split(
    const __hip_bfloat16* __restrict__ Ah,   // hidden bf16 [BD][FD]
    const __hip_bfloat16* __restrict__ MT,   // [FD][FD]  (B stored [N][K])
    const __hip_bfloat16* __restrict__ Ax,   // inputs bf16 [BD][ID]
    const __hip_bfloat16* __restrict__ WT,   // [FD][ID]
    __hip_bfloat16* __restrict__ g0, __hip_bfloat16* __restrict__ g1,
    __hip_bfloat16* __restrict__ gx) {
  __shared__ alignas(16) __hip_bfloat16 As[2][128][32];   // 16 KB
  __shared__ alignas(16) __hip_bfloat16 Bs[2][128][32];   // 16 KB

  const int tid = threadIdx.x;
  const int l = tid & 63, w = tid >> 6;
  const int wr = w >> 1, wc = w & 1;     // wave tile: 64 rows x 64 cols
  const int row0 = blockIdx.x * 128, col0 = blockIdx.y * 128;
  const int bz = blockIdx.z;

  const __hip_bfloat16* A = (bz < 2) ? Ah : Ax;
  const __hip_bfloat16* B = (bz < 2) ? MT : WT;
  const int ld = (bz < 2) ? FD : ID;
  const int kb = (bz == 1) ? 1024 : 0;
  __hip_bfloat16* gout = (bz == 0) ? g0 : (bz == 1) ? g1 : gx;

  v4f acc[4][4];
#pragma unroll
  for (int i = 0; i < 4; i++)
#pragma unroll
    for (int j = 0; j < 4; j++) acc[i][j] = (v4f)0.f;

  // write-side swizzle: lane l stages global (row l>>2, colblk (l&3)^((l>>3)&3))
  const int srow = l >> 2;
  const int scol = ((l & 3) ^ ((l >> 3) & 3)) * 8;
  // read-side swizzle: colblk' = (l>>4) ^ ((l>>1)&3)
  const int rcol = ((l >> 4) ^ ((l >> 1) & 3)) * 8;

  auto stage = [&](int buf, int kt) {
    int k = kb + kt * 32;
#pragma unroll
    for (int i = 0; i < 2; i++) {
      int rr = w * 32 + i * 16;
      gload16(A + (size_t)(row0 + rr + srow) * ld + k + scol, &As[buf][rr][0]);
      gload16(B + (size_t)(col0 + rr + srow) * ld + k + scol, &Bs[buf][rr][0]);
    }
  };
  auto compute = [&](int buf) {
    v8bf a[4], b[4];
#pragma unroll
    for (int mi = 0; mi < 4; mi++)
      a[mi] = *(const v8bf*)&As[buf][wr * 64 + mi * 16 + (l & 15)][rcol];
#pragma unroll
    for (int ni = 0; ni < 4; ni++)
      b[ni] = *(const v8bf*)&Bs[buf][wc * 64 + ni * 16 + (l & 15)][rcol];
#pragma unroll
    for (int mi = 0; mi < 4; mi++)
#pragma unroll
      for (int ni = 0; ni < 4; ni++)
        acc[mi][ni] = __builtin_amdgcn_mfma_f32_16x16x32_bf16(a[mi], b[ni], acc[mi][ni], 0, 0, 0);
  };

  stage(0, 0);
  __syncthreads();
  for (int kt = 0; kt < 32; kt++) {
    if (kt + 1 < 32) stage((kt + 1) & 1, kt + 1);
    compute(kt & 1);
    __syncthreads();
  }

  // write bf16 partial tile
#pragma unroll
  for (int ni = 0; ni < 4; ni++) {
    int gc = col0 + wc * 64 + ni * 16 + (l & 15);
#pragma unroll
    for (int mi = 0; mi < 4; mi++) {
      int gr0 = row0 + wr * 64 + mi * 16 + (l >> 4) * 4;
#pragma unroll
      for (int e = 0; e < 4; e++)
        gout[(size_t)(gr0 + e) * FD + gc] = bf(acc[mi][ni][e]);
    }
  }
}

// ---------- combine: h-update + d_amp + d_ent + ticket scalar finalize ------
__global__ __launch_bounds__(256) void k_comb(
    const __hip_bfloat16* __restrict__ g0, const __hip_bfloat16* __restrict__ g1,
    const __hip_bfloat16* __restrict__ gx, const float* __restrict__ hidden,
    const float* __restrict__ b_in, const float* __restrict__ s_arr,
    const float* __restrict__ qact, const float* __restrict__ pamp,
    const int* tstep, float* scal, float* __restrict__ out) {
  const int row = blockIdx.x;
  const int c = threadIdx.x * 8;
  const size_t base = (size_t)row * FD + c;
  v8bf a0 = *(const v8bf*)(g0 + base);
  v8bf a1 = *(const v8bf*)(g1 + base);
  v8bf axv = *(const v8bf*)(gx + base);
  float4 h0 = *(const float4*)(hidden + base);
  float4 h1 = *(const float4*)(hidden + base + 4);
  float asum = 0.f;
  float o[8];
#pragma unroll
  for (int j = 0; j < 8; j++) {
    float e = (float)a0[j] + (float)a1[j];
    asum += fabsf(e);
    float g = e + (float)axv[j] + b_in[c + j];
    float comb = tanhf(g) + qact[c + j];
    float h = (j < 4) ? (&h0.x)[j] : (&h1.x)[j - 4];
    o[j] = fmaf(s_arr[c + j], comb - h, h);
  }
  *(float4*)&out[base] = make_float4(o[0], o[1], o[2], o[3]);
  *(float4*)&out[base + 4] = make_float4(o[4], o[5], o[6], o[7]);
  *(float4*)&out[(size_t)BD * FD + base] = *(const float4*)&pamp[c];
  *(float4*)&out[(size_t)BD * FD + base + 4] = *(const float4*)&pamp[c + 4];

  for (int off = 32; off; off >>= 1) asum += __shfl_down(asum, off);
  __shared__ float red[4];
  if ((threadIdx.x & 63) == 0) red[threadIdx.x >> 6] = asum;
  __syncthreads();
  if (threadIdx.x == 0) {
    atomicAdd(&scal[0], red[0] + red[1] + red[2] + red[3]);
    __threadfence();
    int* cnt = (int*)(scal + 3);
    if (atomicAdd(cnt, 1) == (int)gridDim.x - 1) {   // last block finalizes
      float tot = atomicAdd(&scal[0], 0.f);          // coherent read of total
      float t = (float)tstep[0];
      float* o3 = out + (size_t)2 * BD * FD;
      o3[0] = expf(-0.01f * t);
      o3[1] = tot / (float)((size_t)BD * FD);
      o3[2] = scal[1] / (float)FD;
      o3[3] = scal[2] / (float)FD;
    }
  }
}

// ---------- fallback: R10 fused kernel (used when ws too small) ----------
__global__ __launch_bounds__(256, 2) void k_gemm_fused(
    const __hip_bfloat16* __restrict__ Ah, const __hip_bfloat16* __restrict__ MT,
    const __hip_bfloat16* __restrict__ Ax, const __hip_bfloat16* __restrict__ WT,
    const float* __restrict__ b_in, const float* __restrict__ s_arr,
    const float* __restrict__ qact, float* ent_sum, float* __restrict__ out) {
  __shared__ alignas(16) __hip_bfloat16 As[3][128][32];
  __shared__ alignas(16) __hip_bfloat16 Bs[3][128][32];
  __shared__ float red[4];
  const int tid = threadIdx.x;
  const int l = tid & 63, w = tid >> 6;
  const int wr = w >> 1, wc = w & 1;
  const int row0 = blockIdx.x * 128, col0 = blockIdx.y * 128;
  v4f acc[4][4];
#pragma unroll
  for (int i = 0; i < 4; i++)
#pragma unroll
    for (int j = 0; j < 4; j++) acc[i][j] = (v4f)0.f;
  const int srow = l >> 2;
  const int scol = ((l & 3) ^ ((l >> 3) & 3)) * 8;
  const int rcol = ((l >> 4) ^ ((l >> 1) & 3)) * 8;
  auto stage = [&](int t) {
    int buf = t % 3;
    const __hip_bfloat16* A = (t < 64) ? Ah : Ax;
    const __hip_bfloat16* B = (t < 64) ? MT : WT;
    int ld = (t < 64) ? FD : ID;
    int k = (t & 63) * 32;
#pragma unroll
    for (int i = 0; i < 2; i++) {
      int rr = w * 32 + i * 16;
      gload16(A + (size_t)(row0 + rr + srow) * ld + k + scol, &As[buf][rr][0]);
      gload16(B + (size_t)(col0 + rr + srow) * ld + k + scol, &Bs[buf][rr][0]);
    }
  };
  auto compute = [&](int t) {
    int buf = t % 3;
    v8bf a[4], b[4];
#pragma unroll
    for (int mi = 0; mi < 4; mi++)
      a[mi] = *(const v8bf*)&As[buf][wr * 64 + mi * 16 + (l & 15)][rcol];
#pragma unroll
    for (int ni = 0; ni < 4; ni++)
      b[ni] = *(const v8bf*)&Bs[buf][wc * 64 + ni * 16 + (l & 15)][rcol];
#pragma unroll
    for (int mi = 0; mi < 4; mi++)
#pragma unroll
      for (int ni = 0; ni < 4; ni++)
        acc[mi][ni] = __builtin_amdgcn_mfma_f32_16x16x32_bf16(a[mi], b[ni], acc[mi][ni], 0, 0, 0);
  };
  stage(0);
  __builtin_amdgcn_sched_barrier(0);
  stage(1);
  float asum = 0.f;
  for (int t = 0; t < 95; t++) {
    asm volatile("s_waitcnt vmcnt(4)" ::: "memory");
    __builtin_amdgcn_s_barrier();
    __builtin_amdgcn_sched_barrier(0);
    if (t + 2 < 96) stage(t + 2);
    compute(t);
    if (t == 63) {
#pragma unroll
      for (int mi = 0; mi < 4; mi++)
#pragma unroll
        for (int ni = 0; ni < 4; ni++)
#pragma unroll
          for (int e = 0; e < 4; e++) asum += fabsf(acc[mi][ni][e]);
    }
  }
  asm volatile("s_waitcnt vmcnt(0)" ::: "memory");
  __builtin_amdgcn_s_barrier();
  __builtin_amdgcn_sched_barrier(0);
  compute(95);
  for (int off = 32; off; off >>= 1) asum += __shfl_down(asum, off);
  if (l == 0) red[w] = asum;
  __syncthreads();
  if (tid == 0) atomicAdd(ent_sum, red[0] + red[1] + red[2] + red[3]);
#pragma unroll
  for (int ni = 0; ni < 4; ni++) {
    int gc = col0 + wc * 64 + ni * 16 + (l & 15);
    float bi = b_in[gc], qa = qact[gc], sj = s_arr[gc];
#pragma unroll
    for (int mi = 0; mi < 4; mi++) {
      int gr0 = row0 + wr * 64 + mi * 16 + (l >> 4) * 4;
#pragma unroll
      for (int e = 0; e < 4; e++) {
        int gr = gr0 + e;
        float comb = tanhf(acc[mi][ni][e] + bi) + qa;
        float h = __bfloat162float(Ah[(size_t)gr * FD + gc]);
        out[(size_t)gr * FD + gc] = fmaf(sj, comb - h, h);
      }
    }
  }
}

__global__ void k_damp(const float* __restrict__ pamp, const float* scal,
                       const int* tstep, float* __restrict__ out1, float* out3) {
  int i = blockIdx.x * 256 + threadIdx.x;
  int c = (i * 4) & (FD - 1);
  ((float4*)out1)[i] = *(const float4*)&pamp[c];
  if (i == 0) {
    float t = (float)tstep[0];
    out3[0] = expf(-0.01f * t);
    out3[1] = scal[0] / (float)((size_t)BD * FD);
    out3[2] = scal[1] / (float)FD;
    out3[3] = scal[2] / (float)FD;
  }
}

extern "C" void kernel_launch(void* const* d_in, const int* in_sizes, int n_in,
                              void* d_out, int out_size, void* d_ws, size_t ws_size,
                              hipStream_t stream) {
  const float* inputs  = (const float*)d_in[0];
  const float* hidden  = (const float*)d_in[1];
  const float* W_in    = (const float*)d_in[2];
  const float* b_in    = (const float*)d_in[3];
  const float* amp_r   = (const float*)d_in[4];
  const float* amp_i   = (const float*)d_in[5];
  const float* phase   = (const float*)d_in[6];
  const float* primary = (const float*)d_in[7];
  const float* ent_mat = (const float*)d_in[8];
  const float* corr    = (const float*)d_in[9];
  const float* W_tau   = (const float*)d_in[10];
  const float* b_tau   = (const float*)d_in[11];
  const float* W_dec   = (const float*)d_in[12];
  const float* b_dec   = (const float*)d_in[13];
  const int*   tstep   = (const int*)d_in[14];

  char* ws = (char*)d_ws;
  __hip_bfloat16* inputs_bf = (__hip_bfloat16*)(ws + 0);         //  8 MB
  __hip_bfloat16* hidden_bf = (__hip_bfloat16*)(ws + 8388608);   // 16 MB
  __hip_bfloat16* WT        = (__hip_bfloat16*)(ws + 25165824);  //  4 MB
  __hip_bfloat16* MT        = (__hip_bfloat16*)(ws + 29360128);  //  8 MB
  __hip_bfloat16* g0        = (__hip_bfloat16*)(ws + 37748736);  // 16 MB
  __hip_bfloat16* g1        = (__hip_bfloat16*)(ws + 54525952);  // 16 MB
  __hip_bfloat16* gx        = (__hip_bfloat16*)(ws + 71303168);  // 16 MB

  const int use_split = (ws_size >= (size_t)88080384 + 65536);
  char* sb = ws + (use_split ? 88080384 : 37748736);
  float* scal    = (float*)(sb);          // [0]=ent_sum [1]=dec_sum [2]=tau_sum [3]=ticket
  float* qs      = (float*)(sb + 16);
  float* pamp    = (float*)(sb + 16 + 8192);
  float* tau_raw = (float*)(sb + 16 + 2 * 8192);
  float* dec_raw = (float*)(sb + 16 + 3 * 8192);
  float* s_arr   = (float*)(sb + 16 + 4 * 8192);
  float* qact    = (float*)(sb + 16 + 5 * 8192);

  float* out = (float*)d_out;

  hipLaunchKernelGGL(k_prep_q, dim3(8), dim3(256), 0, stream,
                     amp_r, amp_i, phase, tstep, qs, pamp, scal, tau_raw, dec_raw);
  hipLaunchKernelGGL(k_cast, dim3(12288), dim3(256), 0, stream,
                     inputs, inputs_bf, BD * ID / 4, hidden, hidden_bf);
  hipLaunchKernelGGL(k_tcast, dim3(64, 32), dim3(32, 8), 0, stream,
                     W_in, (const float*)nullptr, (const float*)nullptr, WT, ID, FD, 0);
  hipLaunchKernelGGL(k_tcast, dim3(64, 64), dim3(32, 8), 0, stream,
                     primary, ent_mat, corr, MT, FD, FD, 1);
  hipLaunchKernelGGL(k_matvec, dim3(8, 16, 2), dim3(256), 0, stream, qs, W_tau, W_dec, tau_raw, dec_raw);
  hipLaunchKernelGGL(k_post, dim3(8), dim3(256), 0, stream, tau_raw, dec_raw, qs, b_tau, b_dec, tstep, s_arr, qact, scal);

  if (use_split) {
    hipLaunchKernelGGL(k_gemm_split, dim3(32, 16, 3), dim3(256), 0, stream,
                       hidden_bf, MT, inputs_bf, WT, g0, g1, gx);
    hipLaunchKernelGGL(k_comb, dim3(4096), dim3(256), 0, stream,
                       g0, g1, gx, hidden, b_in, s_arr, qact, pamp, tstep,
                       scal, out);
  } else {
    hipLaunchKernelGGL(k_gemm_fused, dim3(32, 16), dim3(256), 0, stream,
                       hidden_bf, MT, inputs_bf, WT, b_in, s_arr, qact,
                       &scal[0], out);
    hipLaunchKernelGGL(k_damp, dim3(8192), dim3(256), 0, stream,
                       pamp, scal, tstep, out + (size_t)BD * FD, out + (size_t)2 * BD * FD);
  }
}

// Round 12
// 173.382 us; speedup vs baseline: 1.9009x; 1.9009x over previous
//
#include <hip/hip_runtime.h>
#include <hip/hip_bf16.h>

#define BD 4096
#define ID 1024
#define FD 2048

typedef __bf16 v8bf __attribute__((ext_vector_type(8)));
typedef float  v4f  __attribute__((ext_vector_type(4)));

struct alignas(8) bf4 { __hip_bfloat16 x, y, z, w; };

__device__ inline __hip_bfloat16 bf(float f) { return __float2bfloat16(f); }
__device__ inline float sig(float x) { return 1.f / (1.f + expf(-x)); }

__device__ inline void gload16(const __hip_bfloat16* g, __hip_bfloat16* l) {
  __builtin_amdgcn_global_load_lds(
      (const __attribute__((address_space(1))) void*)g,
      (__attribute__((address_space(3))) void*)l, 16, 0, 0);
}

// ---------- quantum state prep (+ zero accumulators) ----------
__global__ void k_prep_q(const float* ar, const float* ai, const float* ph,
                         const int* tstep, float* qs, float* pamp,
                         float* scal, float* tau_raw, float* dec_raw) {
  int j = blockIdx.x * 256 + threadIdx.x;
  if (j < 4) scal[j] = 0.f;
  if (j < FD) { tau_raw[j] = 0.f; dec_raw[j] = 0.f; }
  if (j >= FD) return;
  float t = (float)tstep[0];
  float4 a = ((const float4*)ar)[j];
  float4 b = ((const float4*)ai)[j];
  float4 p = ((const float4*)ph)[j];
  float sr = 0.f, si = 0.f, pm = 0.f;
  {
    float c, s, rc, ic;
    c = cosf(p.x + 0.1f * t); s = sinf(p.x + 0.1f * t);
    rc = a.x * c; ic = b.x * s; sr += rc; si += ic; pm += rc * rc + ic * ic;
    c = cosf(p.y + 0.1f * t); s = sinf(p.y + 0.1f * t);
    rc = a.y * c; ic = b.y * s; sr += rc; si += ic; pm += rc * rc + ic * ic;
    c = cosf(p.z + 0.1f * t); s = sinf(p.z + 0.1f * t);
    rc = a.z * c; ic = b.z * s; sr += rc; si += ic; pm += rc * rc + ic * ic;
    c = cosf(p.w + 0.1f * t); s = sinf(p.w + 0.1f * t);
    rc = a.w * c; ic = b.w * s; sr += rc; si += ic; pm += rc * rc + ic * ic;
  }
  qs[j] = sr * expf(-si * si);
  pamp[j] = 0.25f * pm;
}

// ---------- f32 -> bf16 cast: inputs then hidden in one launch ----------
__global__ void k_cast(const float* s1, __hip_bfloat16* d1, int n1,
                       const float* s2, __hip_bfloat16* d2) {
  int i = blockIdx.x * blockDim.x + threadIdx.x;
  const float* src = s1; __hip_bfloat16* dst = d1;
  if (i >= n1) { i -= n1; src = s2; dst = d2; }
  float4 v = ((const float4*)src)[i];
  bf4 o{bf(v.x), bf(v.y), bf(v.z), bf(v.w)};
  ((bf4*)dst)[i] = o;
}

// ---------- transpose + cast (+ optional M = P + E*corr[col]) ----------
__global__ void k_tcast(const float* src, const float* src2, const float* corr,
                        __hip_bfloat16* dst, int R, int C, int useM) {
  __shared__ float t[32][33];
  int tx = threadIdx.x, ty = threadIdx.y;   // block (32,8)
  int x = blockIdx.x * 32 + tx;             // src col
  int yb = blockIdx.y * 32;                 // src row base
  float cr = useM ? corr[x] : 0.f;
#pragma unroll
  for (int j = 0; j < 4; j++) {
    int y = yb + ty + j * 8;
    float v = src[(size_t)y * C + x];
    if (useM) v += src2[(size_t)y * C + x] * cr;
    t[ty + j * 8][tx] = v;
  }
  __syncthreads();
#pragma unroll
  for (int j = 0; j < 4; j++) {
    int orow = blockIdx.x * 32 + ty + j * 8;  // = src col
    int ocol = yb + tx;                       // = src row
    dst[(size_t)orow * R + ocol] = bf(t[tx][ty + j * 8]);
  }
}

// ---------- split-K matvec: raw[j] += sum_i qs[i] * W[i][j] ----------
__global__ void k_matvec(const float* qs, const float* Wt, const float* Wd,
                         float* tau_raw, float* dec_raw) {
  int j = blockIdx.x * 256 + threadIdx.x;     // grid.x = 8
  int i0 = blockIdx.y * 128;                  // grid.y = 16
  const float* W = blockIdx.z ? Wd : Wt;      // grid.z = 2
  float* out = blockIdx.z ? dec_raw : tau_raw;
  __shared__ float q[128];
  if (threadIdx.x < 128) q[threadIdx.x] = qs[i0 + threadIdx.x];
  __syncthreads();
  float acc = 0.f;
#pragma unroll 8
  for (int i = 0; i < 128; i++) acc = fmaf(q[i], W[(size_t)(i0 + i) * FD + j], acc);
  atomicAdd(&out[j], acc);
}

// ---------- post: tau_q, s, deco, qact, scalar partials ----------
__global__ void k_post(const float* tau_raw, const float* dec_raw, const float* qs,
                       const float* b_tau, const float* b_dec, const int* tstep,
                       float* s_arr, float* qact, float* scal) {
  int j = blockIdx.x * 256 + threadIdx.x;
  float t = (float)tstep[0];
  float coh = expf(-0.01f * t);
  float tq = (5.f + 45.f * sig(tau_raw[j] + b_tau[j])) / 3.2f;
  s_arr[j] = 0.03125f / tq;                  // dt_q / tau_q, dt_q = 0.1/3.2
  float dec = sig(dec_raw[j] + b_dec[j]);
  qact[j] = qs[j] * dec * coh;
  float tsum = tq, dsum = dec;
  for (int off = 32; off; off >>= 1) {
    tsum += __shfl_down(tsum, off);
    dsum += __shfl_down(dsum, off);
  }
  __shared__ float rt[4], rd[4];
  int w = threadIdx.x >> 6;
  if ((threadIdx.x & 63) == 0) { rt[w] = tsum; rd[w] = dsum; }
  __syncthreads();
  if (threadIdx.x == 0) {
    atomicAdd(&scal[1], rd[0] + rd[1] + rd[2] + rd[3]);
    atomicAdd(&scal[2], rt[0] + rt[1] + rt[2] + rt[3]);
  }
}

// ---------- split-K GEMM: 3 uniform K=1024 parts -> bf16 partial buffers ----
// 128x128 tile, m97 dbuf 2-barrier skeleton + XOR swizzle (0 conflicts).
// grid (32,16,3): bz=0 ent k[0:1024] -> g0; bz=1 ent k[1024:2048] -> g1;
// bz=2 xproj -> gx. 1536 blocks, 32 K-steps each, 4 resident/CU.
__global__ __launch_bounds__(256, 4) void k_gemm_split(
    const __hip_bfloat16* __restrict__ Ah,   // hidden bf16 [BD][FD]
    const __hip_bfloat16* __restrict__ MT,   // [FD][FD]  (B stored [N][K])
    const __hip_bfloat16* __restrict__ Ax,   // inputs bf16 [BD][ID]
    const __hip_bfloat16* __restrict__ WT,   // [FD][ID]
    __hip_bfloat16* __restrict__ g0, __hip_bfloat16* __restrict__ g1,
    __hip_bfloat16* __restrict__ gx) {
  __shared__ alignas(16) __hip_bfloat16 As[2][128][32];   // 16 KB
  __shared__ alignas(16) __hip_bfloat16 Bs[2][128][32];   // 16 KB

  const int tid = threadIdx.x;
  const int l = tid & 63, w = tid >> 6;
  const int wr = w >> 1, wc = w & 1;     // wave tile: 64 rows x 64 cols
  const int row0 = blockIdx.x * 128, col0 = blockIdx.y * 128;
  const int bz = blockIdx.z;

  const __hip_bfloat16* A = (bz < 2) ? Ah : Ax;
  const __hip_bfloat16* B = (bz < 2) ? MT : WT;
  const int ld = (bz < 2) ? FD : ID;
  const int kb = (bz == 1) ? 1024 : 0;
  __hip_bfloat16* gout = (bz == 0) ? g0 : (bz == 1) ? g1 : gx;

  v4f acc[4][4];
#pragma unroll
  for (int i = 0; i < 4; i++)
#pragma unroll
    for (int j = 0; j < 4; j++) acc[i][j] = (v4f)0.f;

  // write-side swizzle: lane l stages global (row l>>2, colblk (l&3)^((l>>3)&3))
  const int srow = l >> 2;
  const int scol = ((l & 3) ^ ((l >> 3) & 3)) * 8;
  // read-side swizzle: colblk' = (l>>4) ^ ((l>>1)&3)
  const int rcol = ((l >> 4) ^ ((l >> 1) & 3)) * 8;

  auto stage = [&](int buf, int kt) {
    int k = kb + kt * 32;
#pragma unroll
    for (int i = 0; i < 2; i++) {
      int rr = w * 32 + i * 16;
      gload16(A + (size_t)(row0 + rr + srow) * ld + k + scol, &As[buf][rr][0]);
      gload16(B + (size_t)(col0 + rr + srow) * ld + k + scol, &Bs[buf][rr][0]);
    }
  };
  auto compute = [&](int buf) {
    v8bf a[4], b[4];
#pragma unroll
    for (int mi = 0; mi < 4; mi++)
      a[mi] = *(const v8bf*)&As[buf][wr * 64 + mi * 16 + (l & 15)][rcol];
#pragma unroll
    for (int ni = 0; ni < 4; ni++)
      b[ni] = *(const v8bf*)&Bs[buf][wc * 64 + ni * 16 + (l & 15)][rcol];
#pragma unroll
    for (int mi = 0; mi < 4; mi++)
#pragma unroll
      for (int ni = 0; ni < 4; ni++)
        acc[mi][ni] = __builtin_amdgcn_mfma_f32_16x16x32_bf16(a[mi], b[ni], acc[mi][ni], 0, 0, 0);
  };

  stage(0, 0);
  __syncthreads();
  for (int kt = 0; kt < 32; kt++) {
    if (kt + 1 < 32) stage((kt + 1) & 1, kt + 1);
    compute(kt & 1);
    __syncthreads();
  }

  // write bf16 partial tile
#pragma unroll
  for (int ni = 0; ni < 4; ni++) {
    int gc = col0 + wc * 64 + ni * 16 + (l & 15);
#pragma unroll
    for (int mi = 0; mi < 4; mi++) {
      int gr0 = row0 + wr * 64 + mi * 16 + (l >> 4) * 4;
#pragma unroll
      for (int e = 0; e < 4; e++)
        gout[(size_t)(gr0 + e) * FD + gc] = bf(acc[mi][ni][e]);
    }
  }
}

// ---------- combine: h-update + d_amp + |ent| block partial (NO atomics) ----
__global__ __launch_bounds__(256) void k_comb(
    const __hip_bfloat16* __restrict__ g0, const __hip_bfloat16* __restrict__ g1,
    const __hip_bfloat16* __restrict__ gx, const float* __restrict__ hidden,
    const float* __restrict__ b_in, const float* __restrict__ s_arr,
    const float* __restrict__ qact, const float* __restrict__ pamp,
    float* __restrict__ entpart, float* __restrict__ out) {
  const int row = blockIdx.x;
  const int c = threadIdx.x * 8;
  const size_t base = (size_t)row * FD + c;
  v8bf a0 = *(const v8bf*)(g0 + base);
  v8bf a1 = *(const v8bf*)(g1 + base);
  v8bf axv = *(const v8bf*)(gx + base);
  float4 h0 = *(const float4*)(hidden + base);
  float4 h1 = *(const float4*)(hidden + base + 4);
  float asum = 0.f;
  float o[8];
#pragma unroll
  for (int j = 0; j < 8; j++) {
    float e = (float)a0[j] + (float)a1[j];
    asum += fabsf(e);
    float g = e + (float)axv[j] + b_in[c + j];
    float comb = tanhf(g) + qact[c + j];
    float h = (j < 4) ? (&h0.x)[j] : (&h1.x)[j - 4];
    o[j] = fmaf(s_arr[c + j], comb - h, h);
  }
  *(float4*)&out[base] = make_float4(o[0], o[1], o[2], o[3]);
  *(float4*)&out[base + 4] = make_float4(o[4], o[5], o[6], o[7]);
  *(float4*)&out[(size_t)BD * FD + base] = *(const float4*)&pamp[c];
  *(float4*)&out[(size_t)BD * FD + base + 4] = *(const float4*)&pamp[c + 4];

  for (int off = 32; off; off >>= 1) asum += __shfl_down(asum, off);
  __shared__ float red[4];
  if ((threadIdx.x & 63) == 0) red[threadIdx.x >> 6] = asum;
  __syncthreads();
  if (threadIdx.x == 0)
    entpart[row] = red[0] + red[1] + red[2] + red[3];   // plain store
}

// ---------- finalize scalars: reduce 4096 |ent| partials ----------
__global__ void k_fin(const float* __restrict__ entpart, const float* scal,
                      const int* tstep, float* out3) {
  float s = 0.f;
  for (int i = threadIdx.x; i < BD; i += 256) s += entpart[i];
  for (int off = 32; off; off >>= 1) s += __shfl_down(s, off);
  __shared__ float red[4];
  if ((threadIdx.x & 63) == 0) red[threadIdx.x >> 6] = s;
  __syncthreads();
  if (threadIdx.x == 0) {
    float tot = red[0] + red[1] + red[2] + red[3];
    float t = (float)tstep[0];
    out3[0] = expf(-0.01f * t);
    out3[1] = tot / (float)((size_t)BD * FD);
    out3[2] = scal[1] / (float)FD;
    out3[3] = scal[2] / (float)FD;
  }
}

extern "C" void kernel_launch(void* const* d_in, const int* in_sizes, int n_in,
                              void* d_out, int out_size, void* d_ws, size_t ws_size,
                              hipStream_t stream) {
  const float* inputs  = (const float*)d_in[0];
  const float* hidden  = (const float*)d_in[1];
  const float* W_in    = (const float*)d_in[2];
  const float* b_in    = (const float*)d_in[3];
  const float* amp_r   = (const float*)d_in[4];
  const float* amp_i   = (const float*)d_in[5];
  const float* phase   = (const float*)d_in[6];
  const float* primary = (const float*)d_in[7];
  const float* ent_mat = (const float*)d_in[8];
  const float* corr    = (const float*)d_in[9];
  const float* W_tau   = (const float*)d_in[10];
  const float* b_tau   = (const float*)d_in[11];
  const float* W_dec   = (const float*)d_in[12];
  const float* b_dec   = (const float*)d_in[13];
  const int*   tstep   = (const int*)d_in[14];

  char* ws = (char*)d_ws;
  __hip_bfloat16* inputs_bf = (__hip_bfloat16*)(ws + 0);         //  8 MB
  __hip_bfloat16* hidden_bf = (__hip_bfloat16*)(ws + 8388608);   // 16 MB
  __hip_bfloat16* WT        = (__hip_bfloat16*)(ws + 25165824);  //  4 MB
  __hip_bfloat16* MT        = (__hip_bfloat16*)(ws + 29360128);  //  8 MB
  __hip_bfloat16* g0        = (__hip_bfloat16*)(ws + 37748736);  // 16 MB
  __hip_bfloat16* g1        = (__hip_bfloat16*)(ws + 54525952);  // 16 MB
  __hip_bfloat16* gx        = (__hip_bfloat16*)(ws + 71303168);  // 16 MB

  char* sb = ws + 88080384;
  float* scal    = (float*)(sb);          // [1]=dec_sum [2]=tau_sum
  float* qs      = (float*)(sb + 16);
  float* pamp    = (float*)(sb + 16 + 8192);
  float* tau_raw = (float*)(sb + 16 + 2 * 8192);
  float* dec_raw = (float*)(sb + 16 + 3 * 8192);
  float* s_arr   = (float*)(sb + 16 + 4 * 8192);
  float* qact    = (float*)(sb + 16 + 5 * 8192);
  float* entpart = (float*)(sb + 16 + 6 * 8192);   // 4096 f32 = 16 KB

  float* out = (float*)d_out;

  hipLaunchKernelGGL(k_prep_q, dim3(8), dim3(256), 0, stream,
                     amp_r, amp_i, phase, tstep, qs, pamp, scal, tau_raw, dec_raw);
  hipLaunchKernelGGL(k_cast, dim3(12288), dim3(256), 0, stream,
                     inputs, inputs_bf, BD * ID / 4, hidden, hidden_bf);
  hipLaunchKernelGGL(k_tcast, dim3(64, 32), dim3(32, 8), 0, stream,
                     W_in, (const float*)nullptr, (const float*)nullptr, WT, ID, FD, 0);
  hipLaunchKernelGGL(k_tcast, dim3(64, 64), dim3(32, 8), 0, stream,
                     primary, ent_mat, corr, MT, FD, FD, 1);
  hipLaunchKernelGGL(k_matvec, dim3(8, 16, 2), dim3(256), 0, stream, qs, W_tau, W_dec, tau_raw, dec_raw);
  hipLaunchKernelGGL(k_post, dim3(8), dim3(256), 0, stream, tau_raw, dec_raw, qs, b_tau, b_dec, tstep, s_arr, qact, scal);
  hipLaunchKernelGGL(k_gemm_split, dim3(32, 16, 3), dim3(256), 0, stream,
                     hidden_bf, MT, inputs_bf, WT, g0, g1, gx);
  hipLaunchKernelGGL(k_comb, dim3(4096), dim3(256), 0, stream,
                     g0, g1, gx, hidden, b_in, s_arr, qact, pamp, entpart, out);
  hipLaunchKernelGGL(k_fin, dim3(1), dim3(256), 0, stream,
                     entpart, scal, tstep, out + (size_t)2 * BD * FD);
}

// Round 13
// 143.046 us; speedup vs baseline: 2.3040x; 1.2121x over previous
//
#include <hip/hip_runtime.h>
#include <hip/hip_bf16.h>

#define BD 4096
#define ID 1024
#define FD 2048

typedef __bf16 v8bf __attribute__((ext_vector_type(8)));
typedef float  v4f  __attribute__((ext_vector_type(4)));

struct alignas(8) bf4 { __hip_bfloat16 x, y, z, w; };

__device__ inline __hip_bfloat16 bf(float f) { return __float2bfloat16(f); }
__device__ inline float sig(float x) { return 1.f / (1.f + expf(-x)); }

__device__ inline void gload16(const __hip_bfloat16* g, __hip_bfloat16* l) {
  __builtin_amdgcn_global_load_lds(
      (const __attribute__((address_space(1))) void*)g,
      (__attribute__((address_space(3))) void*)l, 16, 0, 0);
}

// ---------- quantum state prep (+ zero accumulators) ----------
__global__ void k_prep_q(const float* ar, const float* ai, const float* ph,
                         const int* tstep, float* qs, float* pamp,
                         float* scal, float* tau_raw, float* dec_raw) {
  int j = blockIdx.x * 256 + threadIdx.x;
  if (j < 4) scal[j] = 0.f;
  if (j < FD) { tau_raw[j] = 0.f; dec_raw[j] = 0.f; }
  if (j >= FD) return;
  float t = (float)tstep[0];
  float4 a = ((const float4*)ar)[j];
  float4 b = ((const float4*)ai)[j];
  float4 p = ((const float4*)ph)[j];
  float sr = 0.f, si = 0.f, pm = 0.f;
  {
    float c, s, rc, ic;
    c = cosf(p.x + 0.1f * t); s = sinf(p.x + 0.1f * t);
    rc = a.x * c; ic = b.x * s; sr += rc; si += ic; pm += rc * rc + ic * ic;
    c = cosf(p.y + 0.1f * t); s = sinf(p.y + 0.1f * t);
    rc = a.y * c; ic = b.y * s; sr += rc; si += ic; pm += rc * rc + ic * ic;
    c = cosf(p.z + 0.1f * t); s = sinf(p.z + 0.1f * t);
    rc = a.z * c; ic = b.z * s; sr += rc; si += ic; pm += rc * rc + ic * ic;
    c = cosf(p.w + 0.1f * t); s = sinf(p.w + 0.1f * t);
    rc = a.w * c; ic = b.w * s; sr += rc; si += ic; pm += rc * rc + ic * ic;
  }
  qs[j] = sr * expf(-si * si);
  pamp[j] = 0.25f * pm;
}

// ---------- f32 -> bf16 cast: inputs then hidden in one launch ----------
__global__ void k_cast(const float* s1, __hip_bfloat16* d1, int n1,
                       const float* s2, __hip_bfloat16* d2) {
  int i = blockIdx.x * blockDim.x + threadIdx.x;
  const float* src = s1; __hip_bfloat16* dst = d1;
  if (i >= n1) { i -= n1; src = s2; dst = d2; }
  float4 v = ((const float4*)src)[i];
  bf4 o{bf(v.x), bf(v.y), bf(v.z), bf(v.w)};
  ((bf4*)dst)[i] = o;
}

// ---------- transpose + cast (+ optional M = P + E*corr[col]) ----------
__global__ void k_tcast(const float* src, const float* src2, const float* corr,
                        __hip_bfloat16* dst, int R, int C, int useM) {
  __shared__ float t[32][33];
  int tx = threadIdx.x, ty = threadIdx.y;   // block (32,8)
  int x = blockIdx.x * 32 + tx;             // src col
  int yb = blockIdx.y * 32;                 // src row base
  float cr = useM ? corr[x] : 0.f;
#pragma unroll
  for (int j = 0; j < 4; j++) {
    int y = yb + ty + j * 8;
    float v = src[(size_t)y * C + x];
    if (useM) v += src2[(size_t)y * C + x] * cr;
    t[ty + j * 8][tx] = v;
  }
  __syncthreads();
#pragma unroll
  for (int j = 0; j < 4; j++) {
    int orow = blockIdx.x * 32 + ty + j * 8;  // = src col
    int ocol = yb + tx;                       // = src row
    dst[(size_t)orow * R + ocol] = bf(t[tx][ty + j * 8]);
  }
}

// ---------- split-K matvec: raw[j] += sum_i qs[i] * W[i][j] ----------
__global__ void k_matvec(const float* qs, const float* Wt, const float* Wd,
                         float* tau_raw, float* dec_raw) {
  int j = blockIdx.x * 256 + threadIdx.x;     // grid.x = 8
  int i0 = blockIdx.y * 128;                  // grid.y = 16
  const float* W = blockIdx.z ? Wd : Wt;      // grid.z = 2
  float* out = blockIdx.z ? dec_raw : tau_raw;
  __shared__ float q[128];
  if (threadIdx.x < 128) q[threadIdx.x] = qs[i0 + threadIdx.x];
  __syncthreads();
  float acc = 0.f;
#pragma unroll 8
  for (int i = 0; i < 128; i++) acc = fmaf(q[i], W[(size_t)(i0 + i) * FD + j], acc);
  atomicAdd(&out[j], acc);
}

// ---------- post: tau_q, s, deco, qact, scalar partials ----------
__global__ void k_post(const float* tau_raw, const float* dec_raw, const float* qs,
                       const float* b_tau, const float* b_dec, const int* tstep,
                       float* s_arr, float* qact, float* scal) {
  int j = blockIdx.x * 256 + threadIdx.x;
  float t = (float)tstep[0];
  float coh = expf(-0.01f * t);
  float tq = (5.f + 45.f * sig(tau_raw[j] + b_tau[j])) / 3.2f;
  s_arr[j] = 0.03125f / tq;                  // dt_q / tau_q, dt_q = 0.1/3.2
  float dec = sig(dec_raw[j] + b_dec[j]);
  qact[j] = qs[j] * dec * coh;
  float tsum = tq, dsum = dec;
  for (int off = 32; off; off >>= 1) {
    tsum += __shfl_down(tsum, off);
    dsum += __shfl_down(dsum, off);
  }
  __shared__ float rt[4], rd[4];
  int w = threadIdx.x >> 6;
  if ((threadIdx.x & 63) == 0) { rt[w] = tsum; rd[w] = dsum; }
  __syncthreads();
  if (threadIdx.x == 0) {
    atomicAdd(&scal[1], rd[0] + rd[1] + rd[2] + rd[3]);
    atomicAdd(&scal[2], rt[0] + rt[1] + rt[2] + rt[3]);
  }
}

// ---------- split-K GEMM: 3 uniform K=1024 parts -> bf16 partial buffers ----
// (unchanged from R12: 72 us, MfmaUtil 29%, 0 conflicts)
__global__ __launch_bounds__(256, 4) void k_gemm_split(
    const __hip_bfloat16* __restrict__ Ah,   // hidden bf16 [BD][FD]
    const __hip_bfloat16* __restrict__ MT,   // [FD][FD]  (B stored [N][K])
    const __hip_bfloat16* __restrict__ Ax,   // inputs bf16 [BD][ID]
    const __hip_bfloat16* __restrict__ WT,   // [FD][ID]
    __hip_bfloat16* __restrict__ g0, __hip_bfloat16* __restrict__ g1,
    __hip_bfloat16* __restrict__ gx) {
  __shared__ alignas(16) __hip_bfloat16 As[2][128][32];   // 16 KB
  __shared__ alignas(16) __hip_bfloat16 Bs[2][128][32];   // 16 KB

  const int tid = threadIdx.x;
  const int l = tid & 63, w = tid >> 6;
  const int wr = w >> 1, wc = w & 1;     // wave tile: 64 rows x 64 cols
  const int row0 = blockIdx.x * 128, col0 = blockIdx.y * 128;
  const int bz = blockIdx.z;

  const __hip_bfloat16* A = (bz < 2) ? Ah : Ax;
  const __hip_bfloat16* B = (bz < 2) ? MT : WT;
  const int ld = (bz < 2) ? FD : ID;
  const int kb = (bz == 1) ? 1024 : 0;
  __hip_bfloat16* gout = (bz == 0) ? g0 : (bz == 1) ? g1 : gx;

  v4f acc[4][4];
#pragma unroll
  for (int i = 0; i < 4; i++)
#pragma unroll
    for (int j = 0; j < 4; j++) acc[i][j] = (v4f)0.f;

  const int srow = l >> 2;
  const int scol = ((l & 3) ^ ((l >> 3) & 3)) * 8;
  const int rcol = ((l >> 4) ^ ((l >> 1) & 3)) * 8;

  auto stage = [&](int buf, int kt) {
    int k = kb + kt * 32;
#pragma unroll
    for (int i = 0; i < 2; i++) {
      int rr = w * 32 + i * 16;
      gload16(A + (size_t)(row0 + rr + srow) * ld + k + scol, &As[buf][rr][0]);
      gload16(B + (size_t)(col0 + rr + srow) * ld + k + scol, &Bs[buf][rr][0]);
    }
  };
  auto compute = [&](int buf) {
    v8bf a[4], b[4];
#pragma unroll
    for (int mi = 0; mi < 4; mi++)
      a[mi] = *(const v8bf*)&As[buf][wr * 64 + mi * 16 + (l & 15)][rcol];
#pragma unroll
    for (int ni = 0; ni < 4; ni++)
      b[ni] = *(const v8bf*)&Bs[buf][wc * 64 + ni * 16 + (l & 15)][rcol];
#pragma unroll
    for (int mi = 0; mi < 4; mi++)
#pragma unroll
      for (int ni = 0; ni < 4; ni++)
        acc[mi][ni] = __builtin_amdgcn_mfma_f32_16x16x32_bf16(a[mi], b[ni], acc[mi][ni], 0, 0, 0);
  };

  stage(0, 0);
  __syncthreads();
  for (int kt = 0; kt < 32; kt++) {
    if (kt + 1 < 32) stage((kt + 1) & 1, kt + 1);
    compute(kt & 1);
    __syncthreads();
  }

#pragma unroll
  for (int ni = 0; ni < 4; ni++) {
    int gc = col0 + wc * 64 + ni * 16 + (l & 15);
#pragma unroll
    for (int mi = 0; mi < 4; mi++) {
      int gr0 = row0 + wr * 64 + mi * 16 + (l >> 4) * 4;
#pragma unroll
      for (int e = 0; e < 4; e++)
        gout[(size_t)(gr0 + e) * FD + gc] = bf(acc[mi][ni][e]);
    }
  }
}

// ---------- combine: fully-coalesced h-update + d_amp + |ent| partial -------
// Column-split layout: thread tid owns cols tid*4 and tid*4+1024, so every
// f32 float4 access is 16B/lane contiguous across the wave (no stride-32B
// half-coalesced streams like R12), bf16 reads are 8B/lane contiguous.
__global__ __launch_bounds__(256) void k_comb(
    const __hip_bfloat16* __restrict__ g0, const __hip_bfloat16* __restrict__ g1,
    const __hip_bfloat16* __restrict__ gx, const __hip_bfloat16* __restrict__ hbf,
    const float* __restrict__ b_in, const float* __restrict__ s_arr,
    const float* __restrict__ qact, const float* __restrict__ pamp,
    float* __restrict__ entpart, float* __restrict__ out) {
  const int row = blockIdx.x;
  const size_t rb = (size_t)row * FD;
  float asum = 0.f;
#pragma unroll
  for (int half = 0; half < 2; half++) {
    const int c = half * 1024 + threadIdx.x * 4;
    const size_t base = rb + c;
    bf4 e0 = *(const bf4*)(g0 + base);
    bf4 e1 = *(const bf4*)(g1 + base);
    bf4 xx = *(const bf4*)(gx + base);
    bf4 hh = *(const bf4*)(hbf + base);
    float4 bi = *(const float4*)&b_in[c];
    float4 sj = *(const float4*)&s_arr[c];
    float4 qa = *(const float4*)&qact[c];
    float4 pm = *(const float4*)&pamp[c];
    float o[4];
#pragma unroll
    for (int j = 0; j < 4; j++) {
      float e = __bfloat162float((&e0.x)[j]) + __bfloat162float((&e1.x)[j]);
      asum += fabsf(e);
      float g = e + __bfloat162float((&xx.x)[j]) + (&bi.x)[j];
      float comb = tanhf(g) + (&qa.x)[j];
      float h = __bfloat162float((&hh.x)[j]);
      o[j] = fmaf((&sj.x)[j], comb - h, h);
    }
    *(float4*)&out[base] = make_float4(o[0], o[1], o[2], o[3]);
    *(float4*)&out[(size_t)BD * FD + base] = pm;
  }

  for (int off = 32; off; off >>= 1) asum += __shfl_down(asum, off);
  __shared__ float red[4];
  if ((threadIdx.x & 63) == 0) red[threadIdx.x >> 6] = asum;
  __syncthreads();
  if (threadIdx.x == 0)
    entpart[row] = red[0] + red[1] + red[2] + red[3];   // plain store
}

// ---------- finalize scalars: reduce 4096 |ent| partials ----------
__global__ void k_fin(const float* __restrict__ entpart, const float* scal,
                      const int* tstep, float* out3) {
  float s = 0.f;
  for (int i = threadIdx.x; i < BD; i += 256) s += entpart[i];
  for (int off = 32; off; off >>= 1) s += __shfl_down(s, off);
  __shared__ float red[4];
  if ((threadIdx.x & 63) == 0) red[threadIdx.x >> 6] = s;
  __syncthreads();
  if (threadIdx.x == 0) {
    float tot = red[0] + red[1] + red[2] + red[3];
    float t = (float)tstep[0];
    out3[0] = expf(-0.01f * t);
    out3[1] = tot / (float)((size_t)BD * FD);
    out3[2] = scal[1] / (float)FD;
    out3[3] = scal[2] / (float)FD;
  }
}

extern "C" void kernel_launch(void* const* d_in, const int* in_sizes, int n_in,
                              void* d_out, int out_size, void* d_ws, size_t ws_size,
                              hipStream_t stream) {
  const float* inputs  = (const float*)d_in[0];
  const float* hidden  = (const float*)d_in[1];
  const float* W_in    = (const float*)d_in[2];
  const float* b_in    = (const float*)d_in[3];
  const float* amp_r   = (const float*)d_in[4];
  const float* amp_i   = (const float*)d_in[5];
  const float* phase   = (const float*)d_in[6];
  const float* primary = (const float*)d_in[7];
  const float* ent_mat = (const float*)d_in[8];
  const float* corr    = (const float*)d_in[9];
  const float* W_tau   = (const float*)d_in[10];
  const float* b_tau   = (const float*)d_in[11];
  const float* W_dec   = (const float*)d_in[12];
  const float* b_dec   = (const float*)d_in[13];
  const int*   tstep   = (const int*)d_in[14];

  char* ws = (char*)d_ws;
  __hip_bfloat16* inputs_bf = (__hip_bfloat16*)(ws + 0);         //  8 MB
  __hip_bfloat16* hidden_bf = (__hip_bfloat16*)(ws + 8388608);   // 16 MB
  __hip_bfloat16* WT        = (__hip_bfloat16*)(ws + 25165824);  //  4 MB
  __hip_bfloat16* MT        = (__hip_bfloat16*)(ws + 29360128);  //  8 MB
  __hip_bfloat16* g0        = (__hip_bfloat16*)(ws + 37748736);  // 16 MB
  __hip_bfloat16* g1        = (__hip_bfloat16*)(ws + 54525952);  // 16 MB
  __hip_bfloat16* gx        = (__hip_bfloat16*)(ws + 71303168);  // 16 MB

  char* sb = ws + 88080384;
  float* scal    = (float*)(sb);          // [1]=dec_sum [2]=tau_sum
  float* qs      = (float*)(sb + 16);
  float* pamp    = (float*)(sb + 16 + 8192);
  float* tau_raw = (float*)(sb + 16 + 2 * 8192);
  float* dec_raw = (float*)(sb + 16 + 3 * 8192);
  float* s_arr   = (float*)(sb + 16 + 4 * 8192);
  float* qact    = (float*)(sb + 16 + 5 * 8192);
  float* entpart = (float*)(sb + 16 + 6 * 8192);   // 4096 f32 = 16 KB

  float* out = (float*)d_out;

  hipLaunchKernelGGL(k_prep_q, dim3(8), dim3(256), 0, stream,
                     amp_r, amp_i, phase, tstep, qs, pamp, scal, tau_raw, dec_raw);
  hipLaunchKernelGGL(k_cast, dim3(12288), dim3(256), 0, stream,
                     inputs, inputs_bf, BD * ID / 4, hidden, hidden_bf);
  hipLaunchKernelGGL(k_tcast, dim3(64, 32), dim3(32, 8), 0, stream,
                     W_in, (const float*)nullptr, (const float*)nullptr, WT, ID, FD, 0);
  hipLaunchKernelGGL(k_tcast, dim3(64, 64), dim3(32, 8), 0, stream,
                     primary, ent_mat, corr, MT, FD, FD, 1);
  hipLaunchKernelGGL(k_matvec, dim3(8, 16, 2), dim3(256), 0, stream, qs, W_tau, W_dec, tau_raw, dec_raw);
  hipLaunchKernelGGL(k_post, dim3(8), dim3(256), 0, stream, tau_raw, dec_raw, qs, b_tau, b_dec, tstep, s_arr, qact, scal);
  hipLaunchKernelGGL(k_gemm_split, dim3(32, 16, 3), dim3(256), 0, stream,
                     hidden_bf, MT, inputs_bf, WT, g0, g1, gx);
  hipLaunchKernelGGL(k_comb, dim3(4096), dim3(256), 0, stream,
                     g0, g1, gx, hidden_bf, b_in, s_arr, qact, pamp, entpart, out);
  hipLaunchKernelGGL(k_fin, dim3(1), dim3(256), 0, stream,
                     entpart, scal, tstep, out + (size_t)2 * BD * FD);
}

// Round 14
// 126.432 us; speedup vs baseline: 2.6068x; 1.1314x over previous
//
#include <hip/hip_runtime.h>
#include <hip/hip_bf16.h>

#define BD 4096
#define ID 1024
#define FD 2048

typedef __bf16 v8bf __attribute__((ext_vector_type(8)));
typedef float  v4f  __attribute__((ext_vector_type(4)));

struct alignas(8) bf4 { __hip_bfloat16 x, y, z, w; };

__device__ inline __hip_bfloat16 bf(float f) { return __float2bfloat16(f); }
__device__ inline float sig(float x) { return 1.f / (1.f + expf(-x)); }

__device__ inline void gload16(const __hip_bfloat16* g, __hip_bfloat16* l) {
  __builtin_amdgcn_global_load_lds(
      (const __attribute__((address_space(1))) void*)g,
      (__attribute__((address_space(3))) void*)l, 16, 0, 0);
}

// block-range boundaries inside k_mega
#define MB_CAST  12288   // (BD*ID + BD*FD)/4/256
#define MB_PREP  (MB_CAST + 8)
#define MB_TCW   (MB_PREP + 2048)    // W_in tcast (64,32)
#define MB_TCM   (MB_TCW + 4096)     // M tcast (64,64)
#define MB_MV    (MB_TCM + 256)      // matvec partials 8j x 16p x 2z

// ---------- mega prep kernel: cast | prep_q | tcast W | tcast M | matvec ----
__global__ void k_mega(
    const float* __restrict__ inputs, const float* __restrict__ hidden,
    const float* __restrict__ W_in, const float* __restrict__ primary,
    const float* __restrict__ ent_mat, const float* __restrict__ corr,
    const float* __restrict__ W_tau, const float* __restrict__ W_dec,
    const float* __restrict__ ar, const float* __restrict__ ai,
    const float* __restrict__ ph, const int* __restrict__ tstep,
    __hip_bfloat16* __restrict__ inputs_bf, __hip_bfloat16* __restrict__ hidden_bf,
    __hip_bfloat16* __restrict__ WT, __hip_bfloat16* __restrict__ MT,
    float* __restrict__ qs, float* __restrict__ pamp,
    float* __restrict__ ptau, float* __restrict__ pdec) {
  __shared__ float tbuf[32][33];   // tcast staging
  __shared__ float q[128];         // matvec qs slice
  const int b = blockIdx.x, tid = threadIdx.x;

  if (b < MB_CAST) {               // ---- f32 -> bf16 cast (inputs, hidden)
    int i = b * 256 + tid;
    const float* src = inputs; __hip_bfloat16* dst = inputs_bf;
    int n1 = BD * ID / 4;
    if (i >= n1) { i -= n1; src = hidden; dst = hidden_bf; }
    float4 v = ((const float4*)src)[i];
    bf4 o{bf(v.x), bf(v.y), bf(v.z), bf(v.w)};
    ((bf4*)dst)[i] = o;

  } else if (b < MB_PREP) {        // ---- quantum state prep
    int j = (b - MB_CAST) * 256 + tid;
    float t = (float)tstep[0];
    float4 a = ((const float4*)ar)[j];
    float4 bb = ((const float4*)ai)[j];
    float4 p = ((const float4*)ph)[j];
    float sr = 0.f, si = 0.f, pm = 0.f;
#pragma unroll
    for (int k = 0; k < 4; k++) {
      float pk = (&p.x)[k] + 0.1f * t;
      float rc = (&a.x)[k] * cosf(pk), ic = (&bb.x)[k] * sinf(pk);
      sr += rc; si += ic; pm += rc * rc + ic * ic;
    }
    qs[j] = sr * expf(-si * si);
    pamp[j] = 0.25f * pm;

  } else if (b < MB_TCM) {         // ---- transpose+cast (W_in or M)
    int isM = (b >= MB_TCW);
    int b2 = b - (isM ? MB_TCW : MB_PREP);
    const float* src = isM ? primary : W_in;
    const float* src2 = ent_mat;
    __hip_bfloat16* dst = isM ? MT : WT;
    int C = FD, R = isM ? FD : ID;
    int tx = tid & 31, ty = tid >> 5;
    int x = (b2 & 63) * 32 + tx;          // src col
    int yb = (b2 >> 6) * 32;              // src row base
    float cr = isM ? corr[x] : 0.f;
#pragma unroll
    for (int j = 0; j < 4; j++) {
      int y = yb + ty + j * 8;
      float v = src[(size_t)y * C + x];
      if (isM) v += src2[(size_t)y * C + x] * cr;
      tbuf[ty + j * 8][tx] = v;
    }
    __syncthreads();
#pragma unroll
    for (int j = 0; j < 4; j++) {
      int orow = (b2 & 63) * 32 + ty + j * 8;  // = src col
      int ocol = yb + tx;                      // = src row
      dst[(size_t)orow * R + ocol] = bf(tbuf[tx][ty + j * 8]);
    }

  } else {                         // ---- matvec partials (no atomics)
    int b2 = b - MB_TCM;           // [0,256)
    int jb = b2 & 7, p = (b2 >> 3) & 15, z = b2 >> 7;
    int i0 = p * 128;
    if (tid < 128) {               // recompute qs slice locally
      int i = i0 + tid;
      float t = (float)tstep[0];
      float4 a = ((const float4*)ar)[i];
      float4 bb = ((const float4*)ai)[i];
      float4 pp = ((const float4*)ph)[i];
      float sr = 0.f, si = 0.f;
#pragma unroll
      for (int k = 0; k < 4; k++) {
        float pk = (&pp.x)[k] + 0.1f * t;
        sr += (&a.x)[k] * cosf(pk);
        si += (&bb.x)[k] * sinf(pk);
      }
      q[tid] = sr * expf(-si * si);
    }
    __syncthreads();
    const float* W = z ? W_dec : W_tau;
    float* outp = z ? pdec : ptau;
    int j = jb * 256 + tid;
    float acc = 0.f;
#pragma unroll 8
    for (int i = 0; i < 128; i++)
      acc = fmaf(q[i], W[(size_t)(i0 + i) * FD + j], acc);
    outp[p * FD + j] = acc;        // plain store
  }
}

// ---------- post: reduce partials, tau_q/s/deco/qact, block sums ----------
__global__ void k_post(const float* __restrict__ ptau, const float* __restrict__ pdec,
                       const float* __restrict__ qs, const float* __restrict__ b_tau,
                       const float* __restrict__ b_dec, const int* tstep,
                       float* __restrict__ s_arr, float* __restrict__ qact,
                       float* __restrict__ tpart, float* __restrict__ dpart) {
  int j = blockIdx.x * 256 + threadIdx.x;
  float tr = b_tau[j], dr = b_dec[j];
#pragma unroll
  for (int p = 0; p < 16; p++) {
    tr += ptau[p * FD + j];
    dr += pdec[p * FD + j];
  }
  float t = (float)tstep[0];
  float coh = expf(-0.01f * t);
  float tq = (5.f + 45.f * sig(tr)) / 3.2f;
  s_arr[j] = 0.03125f / tq;
  float dec = sig(dr);
  qact[j] = qs[j] * dec * coh;
  float tsum = tq, dsum = dec;
  for (int off = 32; off; off >>= 1) {
    tsum += __shfl_down(tsum, off);
    dsum += __shfl_down(dsum, off);
  }
  __shared__ float rt[4], rd[4];
  int w = threadIdx.x >> 6;
  if ((threadIdx.x & 63) == 0) { rt[w] = tsum; rd[w] = dsum; }
  __syncthreads();
  if (threadIdx.x == 0) {
    tpart[blockIdx.x] = rt[0] + rt[1] + rt[2] + rt[3];
    dpart[blockIdx.x] = rd[0] + rd[1] + rd[2] + rd[3];
  }
}

// ---------- GEMM 2-part: z=0 ent full K=2048 -> ge; z=1 xproj -> gx ----------
// 128x128 tile, proven 2-barrier dbuf + XOR swizzle (0 conflicts), 1024 blocks
// = single 4/CU dispatch round; long (64-step) blocks dispatch first (z-major).
__global__ __launch_bounds__(256, 4) void k_gemm2(
    const __hip_bfloat16* __restrict__ Ah,   // hidden bf16 [BD][FD]
    const __hip_bfloat16* __restrict__ MT,   // [FD][FD]  (B stored [N][K])
    const __hip_bfloat16* __restrict__ Ax,   // inputs bf16 [BD][ID]
    const __hip_bfloat16* __restrict__ WT,   // [FD][ID]
    __hip_bfloat16* __restrict__ ge, __hip_bfloat16* __restrict__ gx) {
  __shared__ alignas(16) __hip_bfloat16 As[2][128][32];   // 16 KB
  __shared__ alignas(16) __hip_bfloat16 Bs[2][128][32];   // 16 KB

  const int tid = threadIdx.x;
  const int l = tid & 63, w = tid >> 6;
  const int wr = w >> 1, wc = w & 1;     // wave tile: 64 rows x 64 cols
  const int row0 = blockIdx.x * 128, col0 = blockIdx.y * 128;
  const int bz = blockIdx.z;

  const __hip_bfloat16* A = bz ? Ax : Ah;
  const __hip_bfloat16* B = bz ? WT : MT;
  const int ld = bz ? ID : FD;
  const int nkt = bz ? 32 : 64;
  __hip_bfloat16* gout = bz ? gx : ge;

  v4f acc[4][4];
#pragma unroll
  for (int i = 0; i < 4; i++)
#pragma unroll
    for (int j = 0; j < 4; j++) acc[i][j] = (v4f)0.f;

  const int srow = l >> 2;
  const int scol = ((l & 3) ^ ((l >> 3) & 3)) * 8;
  const int rcol = ((l >> 4) ^ ((l >> 1) & 3)) * 8;

  auto stage = [&](int buf, int kt) {
    int k = kt * 32;
#pragma unroll
    for (int i = 0; i < 2; i++) {
      int rr = w * 32 + i * 16;
      gload16(A + (size_t)(row0 + rr + srow) * ld + k + scol, &As[buf][rr][0]);
      gload16(B + (size_t)(col0 + rr + srow) * ld + k + scol, &Bs[buf][rr][0]);
    }
  };
  auto compute = [&](int buf) {
    v8bf a[4], b[4];
#pragma unroll
    for (int mi = 0; mi < 4; mi++)
      a[mi] = *(const v8bf*)&As[buf][wr * 64 + mi * 16 + (l & 15)][rcol];
#pragma unroll
    for (int ni = 0; ni < 4; ni++)
      b[ni] = *(const v8bf*)&Bs[buf][wc * 64 + ni * 16 + (l & 15)][rcol];
#pragma unroll
    for (int mi = 0; mi < 4; mi++)
#pragma unroll
      for (int ni = 0; ni < 4; ni++)
        acc[mi][ni] = __builtin_amdgcn_mfma_f32_16x16x32_bf16(a[mi], b[ni], acc[mi][ni], 0, 0, 0);
  };

  stage(0, 0);
  __syncthreads();
  for (int kt = 0; kt < nkt; kt++) {
    if (kt + 1 < nkt) stage((kt + 1) & 1, kt + 1);
    compute(kt & 1);
    __syncthreads();
  }

#pragma unroll
  for (int ni = 0; ni < 4; ni++) {
    int gc = col0 + wc * 64 + ni * 16 + (l & 15);
#pragma unroll
    for (int mi = 0; mi < 4; mi++) {
      int gr0 = row0 + wr * 64 + mi * 16 + (l >> 4) * 4;
#pragma unroll
      for (int e = 0; e < 4; e++)
        gout[(size_t)(gr0 + e) * FD + gc] = bf(acc[mi][ni][e]);
    }
  }
}

// ---------- combine: coalesced h-update + d_amp + |ent| partial ----------
__global__ __launch_bounds__(256) void k_comb(
    const __hip_bfloat16* __restrict__ ge, const __hip_bfloat16* __restrict__ gx,
    const __hip_bfloat16* __restrict__ hbf,
    const float* __restrict__ b_in, const float* __restrict__ s_arr,
    const float* __restrict__ qact, const float* __restrict__ pamp,
    float* __restrict__ entpart, float* __restrict__ out) {
  const int row = blockIdx.x;
  const size_t rb = (size_t)row * FD;
  float asum = 0.f;
#pragma unroll
  for (int half = 0; half < 2; half++) {
    const int c = half * 1024 + threadIdx.x * 4;
    const size_t base = rb + c;
    bf4 e0 = *(const bf4*)(ge + base);
    bf4 xx = *(const bf4*)(gx + base);
    bf4 hh = *(const bf4*)(hbf + base);
    float4 bi = *(const float4*)&b_in[c];
    float4 sj = *(const float4*)&s_arr[c];
    float4 qa = *(const float4*)&qact[c];
    float4 pm = *(const float4*)&pamp[c];
    float o[4];
#pragma unroll
    for (int j = 0; j < 4; j++) {
      float e = __bfloat162float((&e0.x)[j]);
      asum += fabsf(e);
      float g = e + __bfloat162float((&xx.x)[j]) + (&bi.x)[j];
      float comb = tanhf(g) + (&qa.x)[j];
      float h = __bfloat162float((&hh.x)[j]);
      o[j] = fmaf((&sj.x)[j], comb - h, h);
    }
    *(float4*)&out[base] = make_float4(o[0], o[1], o[2], o[3]);
    *(float4*)&out[(size_t)BD * FD + base] = pm;
  }

  for (int off = 32; off; off >>= 1) asum += __shfl_down(asum, off);
  __shared__ float red[4];
  if ((threadIdx.x & 63) == 0) red[threadIdx.x >> 6] = asum;
  __syncthreads();
  if (threadIdx.x == 0)
    entpart[row] = red[0] + red[1] + red[2] + red[3];
}

// ---------- finalize: reduce entpart + tpart + dpart ----------
__global__ void k_fin(const float* __restrict__ entpart, const float* __restrict__ tpart,
                      const float* __restrict__ dpart, const int* tstep, float* out3) {
  float s = 0.f;
  for (int i = threadIdx.x; i < BD; i += 256) s += entpart[i];
  for (int off = 32; off; off >>= 1) s += __shfl_down(s, off);
  __shared__ float red[4];
  if ((threadIdx.x & 63) == 0) red[threadIdx.x >> 6] = s;
  __syncthreads();
  if (threadIdx.x == 0) {
    float tot = red[0] + red[1] + red[2] + red[3];
    float ts = 0.f, ds = 0.f;
#pragma unroll
    for (int i = 0; i < 8; i++) { ts += tpart[i]; ds += dpart[i]; }
    float t = (float)tstep[0];
    out3[0] = expf(-0.01f * t);
    out3[1] = tot / (float)((size_t)BD * FD);
    out3[2] = ds / (float)FD;
    out3[3] = ts / (float)FD;
  }
}

extern "C" void kernel_launch(void* const* d_in, const int* in_sizes, int n_in,
                              void* d_out, int out_size, void* d_ws, size_t ws_size,
                              hipStream_t stream) {
  const float* inputs  = (const float*)d_in[0];
  const float* hidden  = (const float*)d_in[1];
  const float* W_in    = (const float*)d_in[2];
  const float* b_in    = (const float*)d_in[3];
  const float* amp_r   = (const float*)d_in[4];
  const float* amp_i   = (const float*)d_in[5];
  const float* phase   = (const float*)d_in[6];
  const float* primary = (const float*)d_in[7];
  const float* ent_mat = (const float*)d_in[8];
  const float* corr    = (const float*)d_in[9];
  const float* W_tau   = (const float*)d_in[10];
  const float* b_tau   = (const float*)d_in[11];
  const float* W_dec   = (const float*)d_in[12];
  const float* b_dec   = (const float*)d_in[13];
  const int*   tstep   = (const int*)d_in[14];

  char* ws = (char*)d_ws;
  __hip_bfloat16* inputs_bf = (__hip_bfloat16*)(ws + 0);         //  8 MB
  __hip_bfloat16* hidden_bf = (__hip_bfloat16*)(ws + 8388608);   // 16 MB
  __hip_bfloat16* WT        = (__hip_bfloat16*)(ws + 25165824);  //  4 MB
  __hip_bfloat16* MT        = (__hip_bfloat16*)(ws + 29360128);  //  8 MB
  __hip_bfloat16* ge        = (__hip_bfloat16*)(ws + 37748736);  // 16 MB
  __hip_bfloat16* gx        = (__hip_bfloat16*)(ws + 54525952);  // 16 MB

  char* sb = ws + 71303168;
  float* qs      = (float*)(sb);
  float* pamp    = (float*)(sb + 8192);
  float* s_arr   = (float*)(sb + 2 * 8192);
  float* qact    = (float*)(sb + 3 * 8192);
  float* ptau    = (float*)(sb + 4 * 8192);             // 16x2048 = 128 KB
  float* pdec    = (float*)(sb + 4 * 8192 + 131072);    // 128 KB
  float* entpart = (float*)(sb + 4 * 8192 + 262144);    // 16 KB
  float* tpart   = (float*)(sb + 4 * 8192 + 278528);
  float* dpart   = (float*)(sb + 4 * 8192 + 278528 + 64);

  float* out = (float*)d_out;

  hipLaunchKernelGGL(k_mega, dim3(MB_MV), dim3(256), 0, stream,
                     inputs, hidden, W_in, primary, ent_mat, corr, W_tau, W_dec,
                     amp_r, amp_i, phase, tstep,
                     inputs_bf, hidden_bf, WT, MT, qs, pamp, ptau, pdec);
  hipLaunchKernelGGL(k_post, dim3(8), dim3(256), 0, stream,
                     ptau, pdec, qs, b_tau, b_dec, tstep, s_arr, qact, tpart, dpart);
  hipLaunchKernelGGL(k_gemm2, dim3(32, 16, 2), dim3(256), 0, stream,
                     hidden_bf, MT, inputs_bf, WT, ge, gx);
  hipLaunchKernelGGL(k_comb, dim3(4096), dim3(256), 0, stream,
                     ge, gx, hidden_bf, b_in, s_arr, qact, pamp, entpart, out);
  hipLaunchKernelGGL(k_fin, dim3(1), dim3(256), 0, stream,
                     entpart, tpart, dpart, tstep, out + (size_t)2 * BD * FD);
}

// Round 16
// 125.185 us; speedup vs baseline: 2.6327x; 1.0100x over previous
//
#include <hip/hip_runtime.h>
#include <hip/hip_bf16.h>

#define BD 4096
#define ID 1024
#define FD 2048

typedef __bf16 v8bf __attribute__((ext_vector_type(8)));
typedef float  v4f  __attribute__((ext_vector_type(4)));

struct alignas(8) bf4 { __hip_bfloat16 x, y, z, w; };

__device__ inline __hip_bfloat16 bf(float f) { return __float2bfloat16(f); }
__device__ inline float sig(float x) { return 1.f / (1.f + expf(-x)); }

__device__ inline void gload16(const __hip_bfloat16* g, __hip_bfloat16* l) {
  __builtin_amdgcn_global_load_lds(
      (const __attribute__((address_space(1))) void*)g,
      (__attribute__((address_space(3))) void*)l, 16, 0, 0);
}

// block-range boundaries inside k_mega
#define MB_CAST  12288   // (BD*ID + BD*FD)/4/256
#define MB_PREP  (MB_CAST + 8)
#define MB_TCW   (MB_PREP + 2048)    // W_in tcast (64,32)
#define MB_TCM   (MB_TCW + 4096)     // M tcast (64,64)
#define MB_MV    (MB_TCM + 256)      // matvec partials 8j x 16p x 2z

// ---------- mega prep kernel: cast | prep_q | tcast W | tcast M | matvec ----
__global__ void k_mega(
    const float* __restrict__ inputs, const float* __restrict__ hidden,
    const float* __restrict__ W_in, const float* __restrict__ primary,
    const float* __restrict__ ent_mat, const float* __restrict__ corr,
    const float* __restrict__ W_tau, const float* __restrict__ W_dec,
    const float* __restrict__ ar, const float* __restrict__ ai,
    const float* __restrict__ ph, const int* __restrict__ tstep,
    __hip_bfloat16* __restrict__ inputs_bf, __hip_bfloat16* __restrict__ hidden_bf,
    __hip_bfloat16* __restrict__ WT, __hip_bfloat16* __restrict__ MT,
    float* __restrict__ qs, float* __restrict__ pamp,
    float* __restrict__ ptau, float* __restrict__ pdec) {
  __shared__ float tbuf[32][33];   // tcast staging
  __shared__ float q[128];         // matvec qs slice
  const int b = blockIdx.x, tid = threadIdx.x;

  if (b < MB_CAST) {               // ---- f32 -> bf16 cast (inputs, hidden)
    int i = b * 256 + tid;
    const float* src = inputs; __hip_bfloat16* dst = inputs_bf;
    int n1 = BD * ID / 4;
    if (i >= n1) { i -= n1; src = hidden; dst = hidden_bf; }
    float4 v = ((const float4*)src)[i];
    bf4 o{bf(v.x), bf(v.y), bf(v.z), bf(v.w)};
    ((bf4*)dst)[i] = o;

  } else if (b < MB_PREP) {        // ---- quantum state prep
    int j = (b - MB_CAST) * 256 + tid;
    float t = (float)tstep[0];
    float4 a = ((const float4*)ar)[j];
    float4 bb = ((const float4*)ai)[j];
    float4 p = ((const float4*)ph)[j];
    float sr = 0.f, si = 0.f, pm = 0.f;
#pragma unroll
    for (int k = 0; k < 4; k++) {
      float pk = (&p.x)[k] + 0.1f * t;
      float rc = (&a.x)[k] * cosf(pk), ic = (&bb.x)[k] * sinf(pk);
      sr += rc; si += ic; pm += rc * rc + ic * ic;
    }
    qs[j] = sr * expf(-si * si);
    pamp[j] = 0.25f * pm;

  } else if (b < MB_TCM) {         // ---- transpose+cast (W_in or M)
    int isM = (b >= MB_TCW);
    int b2 = b - (isM ? MB_TCW : MB_PREP);
    const float* src = isM ? primary : W_in;
    const float* src2 = ent_mat;
    __hip_bfloat16* dst = isM ? MT : WT;
    int C = FD, R = isM ? FD : ID;
    int tx = tid & 31, ty = tid >> 5;
    int x = (b2 & 63) * 32 + tx;          // src col
    int yb = (b2 >> 6) * 32;              // src row base
    float cr = isM ? corr[x] : 0.f;
#pragma unroll
    for (int j = 0; j < 4; j++) {
      int y = yb + ty + j * 8;
      float v = src[(size_t)y * C + x];
      if (isM) v += src2[(size_t)y * C + x] * cr;
      tbuf[ty + j * 8][tx] = v;
    }
    __syncthreads();
#pragma unroll
    for (int j = 0; j < 4; j++) {
      int orow = (b2 & 63) * 32 + ty + j * 8;  // = src col
      int ocol = yb + tx;                      // = src row
      dst[(size_t)orow * R + ocol] = bf(tbuf[tx][ty + j * 8]);
    }

  } else {                         // ---- matvec partials (no atomics)
    int b2 = b - MB_TCM;           // [0,256)
    int jb = b2 & 7, p = (b2 >> 3) & 15, z = b2 >> 7;
    int i0 = p * 128;
    if (tid < 128) {               // recompute qs slice locally
      int i = i0 + tid;
      float t = (float)tstep[0];
      float4 a = ((const float4*)ar)[i];
      float4 bb = ((const float4*)ai)[i];
      float4 pp = ((const float4*)ph)[i];
      float sr = 0.f, si = 0.f;
#pragma unroll
      for (int k = 0; k < 4; k++) {
        float pk = (&pp.x)[k] + 0.1f * t;
        sr += (&a.x)[k] * cosf(pk);
        si += (&bb.x)[k] * sinf(pk);
      }
      q[tid] = sr * expf(-si * si);
    }
    __syncthreads();
    const float* W = z ? W_dec : W_tau;
    float* outp = z ? pdec : ptau;
    int j = jb * 256 + tid;
    float acc = 0.f;
#pragma unroll 8
    for (int i = 0; i < 128; i++)
      acc = fmaf(q[i], W[(size_t)(i0 + i) * FD + j], acc);
    outp[p * FD + j] = acc;        // plain store
  }
}

// ---------- post: reduce partials, tau_q/s/deco/qact, block sums ----------
__global__ void k_post(const float* __restrict__ ptau, const float* __restrict__ pdec,
                       const float* __restrict__ qs, const float* __restrict__ b_tau,
                       const float* __restrict__ b_dec, const int* tstep,
                       float* __restrict__ s_arr, float* __restrict__ qact,
                       float* __restrict__ tpart, float* __restrict__ dpart) {
  int j = blockIdx.x * 256 + threadIdx.x;
  float tr = b_tau[j], dr = b_dec[j];
#pragma unroll
  for (int p = 0; p < 16; p++) {
    tr += ptau[p * FD + j];
    dr += pdec[p * FD + j];
  }
  float t = (float)tstep[0];
  float coh = expf(-0.01f * t);
  float tq = (5.f + 45.f * sig(tr)) / 3.2f;
  s_arr[j] = 0.03125f / tq;
  float dec = sig(dr);
  qact[j] = qs[j] * dec * coh;
  float tsum = tq, dsum = dec;
  for (int off = 32; off; off >>= 1) {
    tsum += __shfl_down(tsum, off);
    dsum += __shfl_down(dsum, off);
  }
  __shared__ float rt[4], rd[4];
  int w = threadIdx.x >> 6;
  if ((threadIdx.x & 63) == 0) { rt[w] = tsum; rd[w] = dsum; }
  __syncthreads();
  if (threadIdx.x == 0) {
    tpart[blockIdx.x] = rt[0] + rt[1] + rt[2] + rt[3];
    dpart[blockIdx.x] = rd[0] + rd[1] + rd[2] + rd[3];
  }
}

// ---------- GEMM 2-part: z=0 ent full K=2048 -> ge; z=1 xproj -> gx ----------
// 128x128 tile, proven 2-barrier dbuf + XOR swizzle (0 conflicts), 1024 blocks
// = single 4/CU dispatch round; long (64-step) blocks dispatch first (z-major).
__global__ __launch_bounds__(256, 4) void k_gemm2(
    const __hip_bfloat16* __restrict__ Ah,   // hidden bf16 [BD][FD]
    const __hip_bfloat16* __restrict__ MT,   // [FD][FD]  (B stored [N][K])
    const __hip_bfloat16* __restrict__ Ax,   // inputs bf16 [BD][ID]
    const __hip_bfloat16* __restrict__ WT,   // [FD][ID]
    __hip_bfloat16* __restrict__ ge, __hip_bfloat16* __restrict__ gx) {
  __shared__ alignas(16) __hip_bfloat16 As[2][128][32];   // 16 KB
  __shared__ alignas(16) __hip_bfloat16 Bs[2][128][32];   // 16 KB

  const int tid = threadIdx.x;
  const int l = tid & 63, w = tid >> 6;
  const int wr = w >> 1, wc = w & 1;     // wave tile: 64 rows x 64 cols
  const int row0 = blockIdx.x * 128, col0 = blockIdx.y * 128;
  const int bz = blockIdx.z;

  const __hip_bfloat16* A = bz ? Ax : Ah;
  const __hip_bfloat16* B = bz ? WT : MT;
  const int ld = bz ? ID : FD;
  const int nkt = bz ? 32 : 64;
  __hip_bfloat16* gout = bz ? gx : ge;

  v4f acc[4][4];
#pragma unroll
  for (int i = 0; i < 4; i++)
#pragma unroll
    for (int j = 0; j < 4; j++) acc[i][j] = (v4f)0.f;

  const int srow = l >> 2;
  const int scol = ((l & 3) ^ ((l >> 3) & 3)) * 8;
  const int rcol = ((l >> 4) ^ ((l >> 1) & 3)) * 8;

  auto stage = [&](int buf, int kt) {
    int k = kt * 32;
#pragma unroll
    for (int i = 0; i < 2; i++) {
      int rr = w * 32 + i * 16;
      gload16(A + (size_t)(row0 + rr + srow) * ld + k + scol, &As[buf][rr][0]);
      gload16(B + (size_t)(col0 + rr + srow) * ld + k + scol, &Bs[buf][rr][0]);
    }
  };
  auto compute = [&](int buf) {
    v8bf a[4], b[4];
#pragma unroll
    for (int mi = 0; mi < 4; mi++)
      a[mi] = *(const v8bf*)&As[buf][wr * 64 + mi * 16 + (l & 15)][rcol];
#pragma unroll
    for (int ni = 0; ni < 4; ni++)
      b[ni] = *(const v8bf*)&Bs[buf][wc * 64 + ni * 16 + (l & 15)][rcol];
#pragma unroll
    for (int mi = 0; mi < 4; mi++)
#pragma unroll
      for (int ni = 0; ni < 4; ni++)
        acc[mi][ni] = __builtin_amdgcn_mfma_f32_16x16x32_bf16(a[mi], b[ni], acc[mi][ni], 0, 0, 0);
  };

  stage(0, 0);
  __syncthreads();
  for (int kt = 0; kt < nkt; kt++) {
    if (kt + 1 < nkt) stage((kt + 1) & 1, kt + 1);
    compute(kt & 1);
    __syncthreads();
  }

#pragma unroll
  for (int ni = 0; ni < 4; ni++) {
    int gc = col0 + wc * 64 + ni * 16 + (l & 15);
#pragma unroll
    for (int mi = 0; mi < 4; mi++) {
      int gr0 = row0 + wr * 64 + mi * 16 + (l >> 4) * 4;
#pragma unroll
      for (int e = 0; e < 4; e++)
        gout[(size_t)(gr0 + e) * FD + gc] = bf(acc[mi][ni][e]);
    }
  }
}

// ---------- combine: coalesced h-update + d_amp + |ent| partial ----------
__global__ __launch_bounds__(256) void k_comb(
    const __hip_bfloat16* __restrict__ ge, const __hip_bfloat16* __restrict__ gx,
    const __hip_bfloat16* __restrict__ hbf,
    const float* __restrict__ b_in, const float* __restrict__ s_arr,
    const float* __restrict__ qact, const float* __restrict__ pamp,
    float* __restrict__ entpart, float* __restrict__ out) {
  const int row = blockIdx.x;
  const size_t rb = (size_t)row * FD;
  float asum = 0.f;
#pragma unroll
  for (int half = 0; half < 2; half++) {
    const int c = half * 1024 + threadIdx.x * 4;
    const size_t base = rb + c;
    bf4 e0 = *(const bf4*)(ge + base);
    bf4 xx = *(const bf4*)(gx + base);
    bf4 hh = *(const bf4*)(hbf + base);
    float4 bi = *(const float4*)&b_in[c];
    float4 sj = *(const float4*)&s_arr[c];
    float4 qa = *(const float4*)&qact[c];
    float4 pm = *(const float4*)&pamp[c];
    float o[4];
#pragma unroll
    for (int j = 0; j < 4; j++) {
      float e = __bfloat162float((&e0.x)[j]);
      asum += fabsf(e);
      float g = e + __bfloat162float((&xx.x)[j]) + (&bi.x)[j];
      float comb = tanhf(g) + (&qa.x)[j];
      float h = __bfloat162float((&hh.x)[j]);
      o[j] = fmaf((&sj.x)[j], comb - h, h);
    }
    *(float4*)&out[base] = make_float4(o[0], o[1], o[2], o[3]);
    *(float4*)&out[(size_t)BD * FD + base] = pm;
  }

  for (int off = 32; off; off >>= 1) asum += __shfl_down(asum, off);
  __shared__ float red[4];
  if ((threadIdx.x & 63) == 0) red[threadIdx.x >> 6] = asum;
  __syncthreads();
  if (threadIdx.x == 0)
    entpart[row] = red[0] + red[1] + red[2] + red[3];
}

// ---------- finalize: reduce entpart + tpart + dpart ----------
__global__ void k_fin(const float* __restrict__ entpart, const float* __restrict__ tpart,
                      const float* __restrict__ dpart, const int* tstep, float* out3) {
  float s = 0.f;
  for (int i = threadIdx.x; i < BD; i += 256) s += entpart[i];
  for (int off = 32; off; off >>= 1) s += __shfl_down(s, off);
  __shared__ float red[4];
  if ((threadIdx.x & 63) == 0) red[threadIdx.x >> 6] = s;
  __syncthreads();
  if (threadIdx.x == 0) {
    float tot = red[0] + red[1] + red[2] + red[3];
    float ts = 0.f, ds = 0.f;
#pragma unroll
    for (int i = 0; i < 8; i++) { ts += tpart[i]; ds += dpart[i]; }
    float t = (float)tstep[0];
    out3[0] = expf(-0.01f * t);
    out3[1] = tot / (float)((size_t)BD * FD);
    out3[2] = ds / (float)FD;
    out3[3] = ts / (float)FD;
  }
}

extern "C" void kernel_launch(void* const* d_in, const int* in_sizes, int n_in,
                              void* d_out, int out_size, void* d_ws, size_t ws_size,
                              hipStream_t stream) {
  const float* inputs  = (const float*)d_in[0];
  const float* hidden  = (const float*)d_in[1];
  const float* W_in    = (const float*)d_in[2];
  const float* b_in    = (const float*)d_in[3];
  const float* amp_r   = (const float*)d_in[4];
  const float* amp_i   = (const float*)d_in[5];
  const float* phase   = (const float*)d_in[6];
  const float* primary = (const float*)d_in[7];
  const float* ent_mat = (const float*)d_in[8];
  const float* corr    = (const float*)d_in[9];
  const float* W_tau   = (const float*)d_in[10];
  const float* b_tau   = (const float*)d_in[11];
  const float* W_dec   = (const float*)d_in[12];
  const float* b_dec   = (const float*)d_in[13];
  const int*   tstep   = (const int*)d_in[14];

  char* ws = (char*)d_ws;
  __hip_bfloat16* inputs_bf = (__hip_bfloat16*)(ws + 0);         //  8 MB
  __hip_bfloat16* hidden_bf = (__hip_bfloat16*)(ws + 8388608);   // 16 MB
  __hip_bfloat16* WT        = (__hip_bfloat16*)(ws + 25165824);  //  4 MB
  __hip_bfloat16* MT        = (__hip_bfloat16*)(ws + 29360128);  //  8 MB
  __hip_bfloat16* ge        = (__hip_bfloat16*)(ws + 37748736);  // 16 MB
  __hip_bfloat16* gx        = (__hip_bfloat16*)(ws + 54525952);  // 16 MB

  char* sb = ws + 71303168;
  float* qs      = (float*)(sb);
  float* pamp    = (float*)(sb + 8192);
  float* s_arr   = (float*)(sb + 2 * 8192);
  float* qact    = (float*)(sb + 3 * 8192);
  float* ptau    = (float*)(sb + 4 * 8192);             // 16x2048 = 128 KB
  float* pdec    = (float*)(sb + 4 * 8192 + 131072);    // 128 KB
  float* entpart = (float*)(sb + 4 * 8192 + 262144);    // 16 KB
  float* tpart   = (float*)(sb + 4 * 8192 + 278528);
  float* dpart   = (float*)(sb + 4 * 8192 + 278528 + 64);

  float* out = (float*)d_out;

  hipLaunchKernelGGL(k_mega, dim3(MB_MV), dim3(256), 0, stream,
                     inputs, hidden, W_in, primary, ent_mat, corr, W_tau, W_dec,
                     amp_r, amp_i, phase, tstep,
                     inputs_bf, hidden_bf, WT, MT, qs, pamp, ptau, pdec);
  hipLaunchKernelGGL(k_post, dim3(8), dim3(256), 0, stream,
                     ptau, pdec, qs, b_tau, b_dec, tstep, s_arr, qact, tpart, dpart);
  hipLaunchKernelGGL(k_gemm2, dim3(32, 16, 2), dim3(256), 0, stream,
                     hidden_bf, MT, inputs_bf, WT, ge, gx);
  hipLaunchKernelGGL(k_comb, dim3(4096), dim3(256), 0, stream,
                     ge, gx, hidden_bf, b_in, s_arr, qact, pamp, entpart, out);
  hipLaunchKernelGGL(k_fin, dim3(1), dim3(256), 0, stream,
                     entpart, tpart, dpart, tstep, out + (size_t)2 * BD * FD);
}

// Round 17
// 120.878 us; speedup vs baseline: 2.7265x; 1.0356x over previous
//
#include <hip/hip_runtime.h>
#include <hip/hip_bf16.h>

#define BD 4096
#define ID 1024
#define FD 2048

typedef __bf16 v8bf __attribute__((ext_vector_type(8)));
typedef float  v4f  __attribute__((ext_vector_type(4)));

struct alignas(8) bf4 { __hip_bfloat16 x, y, z, w; };

__device__ inline __hip_bfloat16 bf(float f) { return __float2bfloat16(f); }
__device__ inline float sig(float x) { return 1.f / (1.f + expf(-x)); }
// fast tanh: 1 - 2/(exp(2x)+1); exact at +/-inf, ~1e-6 abs error
__device__ inline float tanh_fast(float x) {
  float e = __expf(2.f * x);
  return 1.f - 2.f * __builtin_amdgcn_rcpf(e + 1.f);
}

__device__ inline void gload16(const __hip_bfloat16* g, __hip_bfloat16* l) {
  __builtin_amdgcn_global_load_lds(
      (const __attribute__((address_space(1))) void*)g,
      (__attribute__((address_space(3))) void*)l, 16, 0, 0);
}

// block-range boundaries inside k_mega
#define MB_CAST  12288   // (BD*ID + BD*FD)/4/256
#define MB_PREP  (MB_CAST + 8)
#define MB_TCW   (MB_PREP + 2048)    // W_in tcast (64,32)
#define MB_TCM   (MB_TCW + 4096)     // M tcast (64,64)
#define MB_MV    (MB_TCM + 256)      // matvec partials 8j x 16p x 2z

// ---------- mega prep kernel: cast | prep_q | tcast W | tcast M | matvec ----
__global__ void k_mega(
    const float* __restrict__ inputs, const float* __restrict__ hidden,
    const float* __restrict__ W_in, const float* __restrict__ primary,
    const float* __restrict__ ent_mat, const float* __restrict__ corr,
    const float* __restrict__ W_tau, const float* __restrict__ W_dec,
    const float* __restrict__ ar, const float* __restrict__ ai,
    const float* __restrict__ ph, const int* __restrict__ tstep,
    __hip_bfloat16* __restrict__ inputs_bf, __hip_bfloat16* __restrict__ hidden_bf,
    __hip_bfloat16* __restrict__ WT, __hip_bfloat16* __restrict__ MT,
    float* __restrict__ qs, float* __restrict__ pamp,
    float* __restrict__ ptau, float* __restrict__ pdec) {
  __shared__ float tbuf[32][33];   // tcast staging
  __shared__ float q[128];         // matvec qs slice
  const int b = blockIdx.x, tid = threadIdx.x;

  if (b < MB_CAST) {               // ---- f32 -> bf16 cast (inputs, hidden)
    int i = b * 256 + tid;
    const float* src = inputs; __hip_bfloat16* dst = inputs_bf;
    int n1 = BD * ID / 4;
    if (i >= n1) { i -= n1; src = hidden; dst = hidden_bf; }
    float4 v = ((const float4*)src)[i];
    bf4 o{bf(v.x), bf(v.y), bf(v.z), bf(v.w)};
    ((bf4*)dst)[i] = o;

  } else if (b < MB_PREP) {        // ---- quantum state prep
    int j = (b - MB_CAST) * 256 + tid;
    float t = (float)tstep[0];
    float4 a = ((const float4*)ar)[j];
    float4 bb = ((const float4*)ai)[j];
    float4 p = ((const float4*)ph)[j];
    float sr = 0.f, si = 0.f, pm = 0.f;
#pragma unroll
    for (int k = 0; k < 4; k++) {
      float pk = (&p.x)[k] + 0.1f * t;
      float rc = (&a.x)[k] * cosf(pk), ic = (&bb.x)[k] * sinf(pk);
      sr += rc; si += ic; pm += rc * rc + ic * ic;
    }
    qs[j] = sr * expf(-si * si);
    pamp[j] = 0.25f * pm;

  } else if (b < MB_TCM) {         // ---- transpose+cast (W_in or M)
    int isM = (b >= MB_TCW);
    int b2 = b - (isM ? MB_TCW : MB_PREP);
    const float* src = isM ? primary : W_in;
    const float* src2 = ent_mat;
    __hip_bfloat16* dst = isM ? MT : WT;
    int C = FD, R = isM ? FD : ID;
    int tx = tid & 31, ty = tid >> 5;
    int x = (b2 & 63) * 32 + tx;          // src col
    int yb = (b2 >> 6) * 32;              // src row base
    float cr = isM ? corr[x] : 0.f;
#pragma unroll
    for (int j = 0; j < 4; j++) {
      int y = yb + ty + j * 8;
      float v = src[(size_t)y * C + x];
      if (isM) v += src2[(size_t)y * C + x] * cr;
      tbuf[ty + j * 8][tx] = v;
    }
    __syncthreads();
#pragma unroll
    for (int j = 0; j < 4; j++) {
      int orow = (b2 & 63) * 32 + ty + j * 8;  // = src col
      int ocol = yb + tx;                      // = src row
      dst[(size_t)orow * R + ocol] = bf(tbuf[tx][ty + j * 8]);
    }

  } else {                         // ---- matvec partials (no atomics)
    int b2 = b - MB_TCM;           // [0,256)
    int jb = b2 & 7, p = (b2 >> 3) & 15, z = b2 >> 7;
    int i0 = p * 128;
    if (tid < 128) {               // recompute qs slice locally
      int i = i0 + tid;
      float t = (float)tstep[0];
      float4 a = ((const float4*)ar)[i];
      float4 bb = ((const float4*)ai)[i];
      float4 pp = ((const float4*)ph)[i];
      float sr = 0.f, si = 0.f;
#pragma unroll
      for (int k = 0; k < 4; k++) {
        float pk = (&pp.x)[k] + 0.1f * t;
        sr += (&a.x)[k] * cosf(pk);
        si += (&bb.x)[k] * sinf(pk);
      }
      q[tid] = sr * expf(-si * si);
    }
    __syncthreads();
    const float* W = z ? W_dec : W_tau;
    float* outp = z ? pdec : ptau;
    int j = jb * 256 + tid;
    float acc = 0.f;
#pragma unroll 8
    for (int i = 0; i < 128; i++)
      acc = fmaf(q[i], W[(size_t)(i0 + i) * FD + j], acc);
    outp[p * FD + j] = acc;        // plain store
  }
}

// ---------- post: reduce partials, tau_q/s/deco/qact, block sums ----------
__global__ void k_post(const float* __restrict__ ptau, const float* __restrict__ pdec,
                       const float* __restrict__ qs, const float* __restrict__ b_tau,
                       const float* __restrict__ b_dec, const int* tstep,
                       float* __restrict__ s_arr, float* __restrict__ qact,
                       float* __restrict__ tpart, float* __restrict__ dpart) {
  int j = blockIdx.x * 256 + threadIdx.x;
  float tr = b_tau[j], dr = b_dec[j];
#pragma unroll
  for (int p = 0; p < 16; p++) {
    tr += ptau[p * FD + j];
    dr += pdec[p * FD + j];
  }
  float t = (float)tstep[0];
  float coh = expf(-0.01f * t);
  float tq = (5.f + 45.f * sig(tr)) / 3.2f;
  s_arr[j] = 0.03125f / tq;
  float dec = sig(dr);
  qact[j] = qs[j] * dec * coh;
  float tsum = tq, dsum = dec;
  for (int off = 32; off; off >>= 1) {
    tsum += __shfl_down(tsum, off);
    dsum += __shfl_down(dsum, off);
  }
  __shared__ float rt[4], rd[4];
  int w = threadIdx.x >> 6;
  if ((threadIdx.x & 63) == 0) { rt[w] = tsum; rd[w] = dsum; }
  __syncthreads();
  if (threadIdx.x == 0) {
    tpart[blockIdx.x] = rt[0] + rt[1] + rt[2] + rt[3];
    dpart[blockIdx.x] = rd[0] + rd[1] + rd[2] + rd[3];
  }
}

// ---------- GEMM 2-part: z=0 ent full K=2048 -> ge (+ |ent| partials);
// z=1 xproj -> gx. 128x128 tile, 2-barrier dbuf + XOR swizzle, 1024 blocks.
__global__ __launch_bounds__(256, 4) void k_gemm2(
    const __hip_bfloat16* __restrict__ Ah,   // hidden bf16 [BD][FD]
    const __hip_bfloat16* __restrict__ MT,   // [FD][FD]  (B stored [N][K])
    const __hip_bfloat16* __restrict__ Ax,   // inputs bf16 [BD][ID]
    const __hip_bfloat16* __restrict__ WT,   // [FD][ID]
    __hip_bfloat16* __restrict__ ge, __hip_bfloat16* __restrict__ gx,
    float* __restrict__ entpart) {
  __shared__ alignas(16) __hip_bfloat16 As[2][128][32];   // 16 KB
  __shared__ alignas(16) __hip_bfloat16 Bs[2][128][32];   // 16 KB

  const int tid = threadIdx.x;
  const int l = tid & 63, w = tid >> 6;
  const int wr = w >> 1, wc = w & 1;     // wave tile: 64 rows x 64 cols
  const int row0 = blockIdx.x * 128, col0 = blockIdx.y * 128;
  const int bz = blockIdx.z;

  const __hip_bfloat16* A = bz ? Ax : Ah;
  const __hip_bfloat16* B = bz ? WT : MT;
  const int ld = bz ? ID : FD;
  const int nkt = bz ? 32 : 64;
  __hip_bfloat16* gout = bz ? gx : ge;

  v4f acc[4][4];
#pragma unroll
  for (int i = 0; i < 4; i++)
#pragma unroll
    for (int j = 0; j < 4; j++) acc[i][j] = (v4f)0.f;

  const int srow = l >> 2;
  const int scol = ((l & 3) ^ ((l >> 3) & 3)) * 8;
  const int rcol = ((l >> 4) ^ ((l >> 1) & 3)) * 8;

  auto stage = [&](int buf, int kt) {
    int k = kt * 32;
#pragma unroll
    for (int i = 0; i < 2; i++) {
      int rr = w * 32 + i * 16;
      gload16(A + (size_t)(row0 + rr + srow) * ld + k + scol, &As[buf][rr][0]);
      gload16(B + (size_t)(col0 + rr + srow) * ld + k + scol, &Bs[buf][rr][0]);
    }
  };
  auto compute = [&](int buf) {
    v8bf a[4], b[4];
#pragma unroll
    for (int mi = 0; mi < 4; mi++)
      a[mi] = *(const v8bf*)&As[buf][wr * 64 + mi * 16 + (l & 15)][rcol];
#pragma unroll
    for (int ni = 0; ni < 4; ni++)
      b[ni] = *(const v8bf*)&Bs[buf][wc * 64 + ni * 16 + (l & 15)][rcol];
#pragma unroll
    for (int mi = 0; mi < 4; mi++)
#pragma unroll
      for (int ni = 0; ni < 4; ni++)
        acc[mi][ni] = __builtin_amdgcn_mfma_f32_16x16x32_bf16(a[mi], b[ni], acc[mi][ni], 0, 0, 0);
  };

  stage(0, 0);
  __syncthreads();
  for (int kt = 0; kt < nkt; kt++) {
    if (kt + 1 < nkt) stage((kt + 1) & 1, kt + 1);
    compute(kt & 1);
    __syncthreads();
  }

  float asum = 0.f;
#pragma unroll
  for (int ni = 0; ni < 4; ni++) {
    int gc = col0 + wc * 64 + ni * 16 + (l & 15);
#pragma unroll
    for (int mi = 0; mi < 4; mi++) {
      int gr0 = row0 + wr * 64 + mi * 16 + (l >> 4) * 4;
#pragma unroll
      for (int e = 0; e < 4; e++) {
        float v = acc[mi][ni][e];
        asum += fabsf(v);
        gout[(size_t)(gr0 + e) * FD + gc] = bf(v);
      }
    }
  }
  if (bz == 0) {   // |ent| per-wave partial (f32-accurate, free here)
    for (int off = 32; off; off >>= 1) asum += __shfl_down(asum, off);
    if (l == 0) entpart[(blockIdx.x * 16 + blockIdx.y) * 4 + w] = asum;
  }
}

// ---------- combine: coalesced streaming h-update + d_amp (no reduce) ------
__global__ __launch_bounds__(256) void k_comb(
    const __hip_bfloat16* __restrict__ ge, const __hip_bfloat16* __restrict__ gx,
    const __hip_bfloat16* __restrict__ hbf,
    const float* __restrict__ b_in, const float* __restrict__ s_arr,
    const float* __restrict__ qact, const float* __restrict__ pamp,
    float* __restrict__ out) {
  const int row = blockIdx.x;
  const size_t rb = (size_t)row * FD;
#pragma unroll
  for (int half = 0; half < 2; half++) {
    const int c = half * 1024 + threadIdx.x * 4;
    const size_t base = rb + c;
    bf4 e0 = *(const bf4*)(ge + base);
    bf4 xx = *(const bf4*)(gx + base);
    bf4 hh = *(const bf4*)(hbf + base);
    float4 bi = *(const float4*)&b_in[c];
    float4 sj = *(const float4*)&s_arr[c];
    float4 qa = *(const float4*)&qact[c];
    float4 pm = *(const float4*)&pamp[c];
    float o[4];
#pragma unroll
    for (int j = 0; j < 4; j++) {
      float g = __bfloat162float((&e0.x)[j]) + __bfloat162float((&xx.x)[j]) + (&bi.x)[j];
      float comb = tanh_fast(g) + (&qa.x)[j];
      float h = __bfloat162float((&hh.x)[j]);
      o[j] = fmaf((&sj.x)[j], comb - h, h);
    }
    *(float4*)&out[base] = make_float4(o[0], o[1], o[2], o[3]);
    *(float4*)&out[(size_t)BD * FD + base] = pm;
  }
}

// ---------- finalize: reduce entpart(2048) + tpart + dpart ----------
__global__ void k_fin(const float* __restrict__ entpart, const float* __restrict__ tpart,
                      const float* __restrict__ dpart, const int* tstep, float* out3) {
  float s = 0.f;
  for (int i = threadIdx.x; i < 2048; i += 256) s += entpart[i];
  for (int off = 32; off; off >>= 1) s += __shfl_down(s, off);
  __shared__ float red[4];
  if ((threadIdx.x & 63) == 0) red[threadIdx.x >> 6] = s;
  __syncthreads();
  if (threadIdx.x == 0) {
    float tot = red[0] + red[1] + red[2] + red[3];
    float ts = 0.f, ds = 0.f;
#pragma unroll
    for (int i = 0; i < 8; i++) { ts += tpart[i]; ds += dpart[i]; }
    float t = (float)tstep[0];
    out3[0] = expf(-0.01f * t);
    out3[1] = tot / (float)((size_t)BD * FD);
    out3[2] = ds / (float)FD;
    out3[3] = ts / (float)FD;
  }
}

extern "C" void kernel_launch(void* const* d_in, const int* in_sizes, int n_in,
                              void* d_out, int out_size, void* d_ws, size_t ws_size,
                              hipStream_t stream) {
  const float* inputs  = (const float*)d_in[0];
  const float* hidden  = (const float*)d_in[1];
  const float* W_in    = (const float*)d_in[2];
  const float* b_in    = (const float*)d_in[3];
  const float* amp_r   = (const float*)d_in[4];
  const float* amp_i   = (const float*)d_in[5];
  const float* phase   = (const float*)d_in[6];
  const float* primary = (const float*)d_in[7];
  const float* ent_mat = (const float*)d_in[8];
  const float* corr    = (const float*)d_in[9];
  const float* W_tau   = (const float*)d_in[10];
  const float* b_tau   = (const float*)d_in[11];
  const float* W_dec   = (const float*)d_in[12];
  const float* b_dec   = (const float*)d_in[13];
  const int*   tstep   = (const int*)d_in[14];

  char* ws = (char*)d_ws;
  __hip_bfloat16* inputs_bf = (__hip_bfloat16*)(ws + 0);         //  8 MB
  __hip_bfloat16* hidden_bf = (__hip_bfloat16*)(ws + 8388608);   // 16 MB
  __hip_bfloat16* WT        = (__hip_bfloat16*)(ws + 25165824);  //  4 MB
  __hip_bfloat16* MT        = (__hip_bfloat16*)(ws + 29360128);  //  8 MB
  __hip_bfloat16* ge        = (__hip_bfloat16*)(ws + 37748736);  // 16 MB
  __hip_bfloat16* gx        = (__hip_bfloat16*)(ws + 54525952);  // 16 MB

  char* sb = ws + 71303168;
  float* qs      = (float*)(sb);
  float* pamp    = (float*)(sb + 8192);
  float* s_arr   = (float*)(sb + 2 * 8192);
  float* qact    = (float*)(sb + 3 * 8192);
  float* ptau    = (float*)(sb + 4 * 8192);             // 16x2048 = 128 KB
  float* pdec    = (float*)(sb + 4 * 8192 + 131072);    // 128 KB
  float* entpart = (float*)(sb + 4 * 8192 + 262144);    // 2048 f32 = 8 KB
  float* tpart   = (float*)(sb + 4 * 8192 + 262144 + 8192);
  float* dpart   = (float*)(sb + 4 * 8192 + 262144 + 8192 + 64);

  float* out = (float*)d_out;

  hipLaunchKernelGGL(k_mega, dim3(MB_MV), dim3(256), 0, stream,
                     inputs, hidden, W_in, primary, ent_mat, corr, W_tau, W_dec,
                     amp_r, amp_i, phase, tstep,
                     inputs_bf, hidden_bf, WT, MT, qs, pamp, ptau, pdec);
  hipLaunchKernelGGL(k_post, dim3(8), dim3(256), 0, stream,
                     ptau, pdec, qs, b_tau, b_dec, tstep, s_arr, qact, tpart, dpart);
  hipLaunchKernelGGL(k_gemm2, dim3(32, 16, 2), dim3(256), 0, stream,
                     hidden_bf, MT, inputs_bf, WT, ge, gx, entpart);
  hipLaunchKernelGGL(k_comb, dim3(4096), dim3(256), 0, stream,
                     ge, gx, hidden_bf, b_in, s_arr, qact, pamp, out);
  hipLaunchKernelGGL(k_fin, dim3(1), dim3(256), 0, stream,
                     entpart, tpart, dpart, tstep, out + (size_t)2 * BD * FD);
}